// Round 6
// baseline (233.317 us; speedup 1.0000x reference)
//
#include <hip/hip_runtime.h>

// GAT spatio-temporal model — bf16 MFMA multi-kernel pipeline with
// XCD-aware block swizzles and pipelined V staging.
// B=8, N=512, Din=64, H=8, F=128, L=2.

constexpr int B = 8, N = 512, DIN = 64, H = 8, F = 128;
constexpr int BN = B * N;          // 4096
constexpr float ALPHA_LR = 0.2f;   // LeakyReLU slope
constexpr float EPS_LN = 1e-5f;
constexpr float FLOW = -3.0e38f;   // "-inf" substitute

typedef __attribute__((ext_vector_type(8))) short short8;  // 8 bf16
typedef __attribute__((ext_vector_type(4))) float f32x4;

__device__ __forceinline__ f32x4 mfma16(short8 a, short8 b, f32x4 c) {
  return __builtin_amdgcn_mfma_f32_16x16x32_bf16(a, b, c, 0, 0, 0);
}

__device__ __forceinline__ short f2bf(float f) {  // RNE f32 -> bf16 bits
  union { float f; unsigned u; } v;
  v.f = f;
  unsigned r = v.u + 0x7FFFu + ((v.u >> 16) & 1u);
  return (short)(r >> 16);
}

struct KParams {
  const float* x; const int* adj; const float* Wp; const float* bp;
  const float* W_heads; const float* a_heads; const float* W_out;
  const float* a_out; const float* ln_g; const float* ln_b;
  float* h; short* hb; unsigned long long* amask; short* WTh; short* WoT;
  short* hhT; short* multi; short* hsT; float* sA; float* dout;
};

// ================= setup: zero sA | adjmask | proj_in | transposes ========
// grid 512 x 256
__global__ __launch_bounds__(256) void g_setup(KParams P) {
  __shared__ float T[32][33];
  __shared__ float xr[2][64];
  int bid = blockIdx.x, tid = threadIdx.x;
  for (int i = tid; i < 288; i += 256) P.sA[(size_t)bid * 288 + i] = 0.f;
  {  // adjacency -> 64-bit masks (batched loads)
    int lane = tid & 63, wv = tid >> 6;
    int v[16];
#pragma unroll
    for (int j = 0; j < 16; j++) {
      int w = (bid + j * 512) * 4 + wv;
      v[j] = P.adj[(size_t)w * 64 + lane];
    }
#pragma unroll
    for (int j = 0; j < 16; j++) {
      int w = (bid + j * 512) * 4 + wv;
      unsigned long long m = __ballot(v[j] > 0);
      if (lane == 0) P.amask[w] = m;
    }
  }
  {  // input projection: h = relu(x@Wp+bp), 2 rows per unit
    int half = tid >> 7, f = tid & 127;
    for (int u = bid; u < 2048; u += 512) {
      int row = u * 2 + half;
      __syncthreads();
      if (f < 64) xr[half][f] = P.x[(size_t)row * DIN + f];
      __syncthreads();
      float acc = P.bp[f];
#pragma unroll
      for (int i = 0; i < DIN; i++)
        acc = fmaf(xr[half][i], P.Wp[i * F + f], acc);
      acc = fmaxf(acc, 0.f);
      P.h[(size_t)row * F + f] = acc;
      P.hb[(size_t)row * F + f] = f2bf(acc);
    }
  }
  {  // weight transposes f32 [bt][R][C] -> bf16 [bt][C][R], one 32x32 tile
    const float* in; short* out; int R, C, bx, by, bt;
    if (bid < 256) {
      in = P.W_heads; out = P.WTh; R = 128; C = 128;
      bx = bid & 3; by = (bid >> 2) & 3; bt = bid >> 4;
    } else {
      int i = bid - 256;
      in = P.W_out; out = P.WoT; R = 1024; C = 128;
      bx = i & 3; by = (i >> 2) & 31; bt = i >> 7;
    }
    int c0 = bx * 32, r0 = by * 32;
    const float* ip = in + (size_t)bt * R * C;
    short* op = out + (size_t)bt * R * C;
    __syncthreads();
    {
      int r = tid >> 3, c4 = (tid & 7) * 4;
      float4 v = *(const float4*)(ip + (size_t)(r0 + r) * C + c0 + c4);
      T[r][c4] = v.x; T[r][c4 + 1] = v.y; T[r][c4 + 2] = v.z; T[r][c4 + 3] = v.w;
    }
    __syncthreads();
    {
      int cr = tid >> 3, q = (tid & 7) * 4;
      short4 o;
      o.x = f2bf(T[q][cr]); o.y = f2bf(T[q + 1][cr]);
      o.z = f2bf(T[q + 2][cr]); o.w = f2bf(T[q + 3][cr]);
      *(short4*)(op + (size_t)(c0 + cr) * R + r0 + q) = o;
    }
  }
}

// ====== head projection: hhT[bh][f_out][n] = WT[h].hb^T, + s1/s2 epilogue ==
// grid 512: b = bid&7 (XCD-pinned: all blocks reading hb[b] share an XCD)
__global__ __launch_bounds__(256) void g_proj_heads(KParams P, int l) {
  constexpr int LK = 136;
  __shared__ short As[64 * LK];
  __shared__ short Bs[128 * LK];
  const short* WT = P.WTh + (size_t)l * H * F * F;
  const float* ah_base = P.a_heads + (size_t)l * H * 2 * F;
  float* s1 = P.sA + (size_t)l * 73728;
  float* s2 = s1 + 32768;
  int bid = blockIdx.x, tid = threadIdx.x;
  int b = bid & 7, u = bid >> 3;
  int hd = u & 7, ft = (u >> 3) & 1, nt = u >> 4;
  int bh = b * 8 + hd, n0 = nt * 128;
  int lane = tid & 63, w = tid >> 6;
  {
    int r = tid >> 2, q = tid & 3;
    const uint4* g = (const uint4*)(WT + ((size_t)hd * F + ft * 64 + r) * F) + q * 4;
    uint4* lp = (uint4*)(As + r * LK) + q * 4;
    lp[0] = g[0]; lp[1] = g[1]; lp[2] = g[2]; lp[3] = g[3];
  }
  {
    int q = tid & 3;
    for (int r = tid >> 2; r < 128; r += 64) {
      const uint4* g = (const uint4*)(P.hb + ((size_t)(b * N + n0 + r)) * F) + q * 4;
      uint4* lp = (uint4*)(Bs + r * LK) + q * 4;
      lp[0] = g[0]; lp[1] = g[1]; lp[2] = g[2]; lp[3] = g[3];
    }
  }
  __syncthreads();
  int arow = lane & 15, koff = (lane >> 4) * 8;
  f32x4 acc[4][2] = {};
#pragma unroll
  for (int ks = 0; ks < 4; ks++) {
    short8 a[4], bb[2];
#pragma unroll
    for (int rt = 0; rt < 4; rt++)
      a[rt] = *(const short8*)(As + (rt * 16 + arow) * LK + ks * 32 + koff);
#pragma unroll
    for (int cj = 0; cj < 2; cj++)
      bb[cj] = *(const short8*)(Bs + ((2 * w + cj) * 16 + arow) * LK + ks * 32 + koff);
#pragma unroll
    for (int rt = 0; rt < 4; rt++)
#pragma unroll
      for (int cj = 0; cj < 2; cj++)
        acc[rt][cj] = mfma16(a[rt], bb[cj], acc[rt][cj]);
  }
  short* outp = P.hhT + (size_t)bh * F * N;
  int crow0 = (lane >> 4) * 4;
#pragma unroll
  for (int rt = 0; rt < 4; rt++)
#pragma unroll
    for (int cj = 0; cj < 2; cj++) {
      int fo = ft * 64 + rt * 16 + crow0;
      int n = n0 + (2 * w + cj) * 16 + arow;
#pragma unroll
      for (int r = 0; r < 4; r++)
        outp[(size_t)(fo + r) * N + n] = f2bf(acc[rt][cj][r]);
    }
  const float* ah = ah_base + (size_t)hd * 2 * F;
  float pa1[2] = {0.f, 0.f}, pa2[2] = {0.f, 0.f};
#pragma unroll
  for (int rt = 0; rt < 4; rt++) {
    int fo = ft * 64 + rt * 16 + crow0;
#pragma unroll
    for (int r = 0; r < 4; r++) {
      float a1v = ah[fo + r], a2v = ah[F + fo + r];
      pa1[0] = fmaf(a1v, acc[rt][0][r], pa1[0]);
      pa1[1] = fmaf(a1v, acc[rt][1][r], pa1[1]);
      pa2[0] = fmaf(a2v, acc[rt][0][r], pa2[0]);
      pa2[1] = fmaf(a2v, acc[rt][1][r], pa2[1]);
    }
  }
#pragma unroll
  for (int cj = 0; cj < 2; cj++) {
    float v1 = pa1[cj], v2 = pa2[cj];
    v1 += __shfl_xor(v1, 16); v1 += __shfl_xor(v1, 32);
    v2 += __shfl_xor(v2, 16); v2 += __shfl_xor(v2, 32);
    if (lane < 16) {
      int n = n0 + (2 * w + cj) * 16 + lane;
      atomicAdd(&s1[(size_t)bh * N + n], v1);
      atomicAdd(&s2[(size_t)bh * N + n], v2);
    }
  }
}

// ====== attention, 8 heads, single-pass softmax, ELU -> multi (bf16) ======
// grid 512: bh = bid&63 (stride-64 Q-tiles of one bh share an XCD -> V from L2)
__global__ __launch_bounds__(256) void g_attn_heads(KParams P, int l) {
  constexpr int LVK = 136;
  __shared__ short Vs[128 * LVK];
  __shared__ short Pf[16 * 64 * 8];
  __shared__ float s2all[512];
  __shared__ float s1r[64], mrow[64], linv[64];
  __shared__ float red[64][4];
  const float* s1g = P.sA + (size_t)l * 73728;
  const float* s2g = s1g + 32768;
  int bid = blockIdx.x, tid = threadIdx.x;
  int bh = bid & 63, nt = bid >> 6;
  int b = bh >> 3, n0 = nt * 64;
  int lane = tid & 63, w = tid >> 6;
  sm_pre:;
  s2all[tid] = s2g[(size_t)bh * N + tid];
  s2all[tid + 256] = s2g[(size_t)bh * N + tid + 256];
  if (tid < 64) s1r[tid] = s1g[(size_t)bh * N + n0 + tid];
  const short* Vg = P.hhT + (size_t)bh * F * N;
  // prologue: issue chunk-0 V loads (overlap the softmax prepass)
  int fr = tid >> 1, hf = tid & 1;
  uint4 vreg[8];
  {
    const uint4* g4 = (const uint4*)(Vg + (size_t)fr * N + 0 + hf * 64);
#pragma unroll
    for (int k = 0; k < 8; k++) vreg[k] = g4[k];
  }
  __syncthreads();
  {  // prepass: per-row masked max of s2 (LeakyReLU monotone)
    const unsigned long long* mq = P.amask + ((size_t)(b * N + n0 + lane)) * 8;
    float mx = FLOW;
#pragma unroll
    for (int j = 0; j < 2; j++) {
      unsigned long long mb = mq[w * 2 + j];
      int base = w * 128 + j * 64;
      unsigned lo = (unsigned)mb, hi = (unsigned)(mb >> 32);
#pragma unroll
      for (int k = 0; k < 32; k++) {
        mx = ((lo >> k) & 1u) ? fmaxf(mx, s2all[base + k]) : mx;
        mx = ((hi >> k) & 1u) ? fmaxf(mx, s2all[base + 32 + k]) : mx;
      }
    }
    red[lane][w] = mx;
  }
  __syncthreads();
  if (tid < 64) {
    float m2 = fmaxf(fmaxf(red[tid][0], red[tid][1]),
                     fmaxf(red[tid][2], red[tid][3]));
    float xm = s1r[tid] + m2;
    mrow[tid] = xm > 0.f ? xm : ALPHA_LR * xm;
  }
  float lp = 0.f;
  int arow = lane & 15, koff = (lane >> 4) * 8;
  f32x4 acc[4][2] = {};
  const unsigned long long* mp = P.amask + ((size_t)(b * N + n0 + lane)) * 8;
  for (int mc = 0; mc < 4; mc++) {
    int m0 = mc * 128;
    __syncthreads();  // A: prior MFMA done with Vs/Pf; drains our V loads
    {                 // store prefetched V chunk to LDS
      uint4* l4 = (uint4*)(Vs + fr * LVK + hf * 64);
#pragma unroll
      for (int k = 0; k < 8; k++) l4[k] = vreg[k];
    }
    {  // P: row = lane, k-range = w*32..+32, A-fragment order
      float s1v = s1r[lane], mr = mrow[lane];
      unsigned bits = (unsigned)(mp[mc * 2 + (w >> 1)] >> ((w & 1) * 32));
      short* pbase = Pf + (((lane >> 4) * 4 + w) * 64) * 8;
#pragma unroll
      for (int q = 0; q < 4; q++) {
        short8 pk;
#pragma unroll
        for (int j = 0; j < 8; j++) {
          float xv = s1v + s2all[m0 + w * 32 + q * 8 + j];
          xv = xv > 0.f ? xv : ALPHA_LR * xv;
          float p = __expf(xv - mr);
          p = ((bits >> (q * 8 + j)) & 1u) ? p : 0.f;
          lp += p;
          pk[j] = f2bf(p);
        }
        *(short8*)(pbase + ((q << 4) | (lane & 15)) * 8) = pk;
      }
    }
    __syncthreads();  // B
    if (mc < 3) {  // issue next chunk's loads AFTER the barrier: overlap MFMA
      const uint4* g4 = (const uint4*)(Vg + (size_t)fr * N + (m0 + 128) + hf * 64);
#pragma unroll
      for (int k = 0; k < 8; k++) vreg[k] = g4[k];
    }
#pragma unroll
    for (int ks = 0; ks < 4; ks++) {
      short8 a[4];
#pragma unroll
      for (int rt = 0; rt < 4; rt++)
        a[rt] = *(const short8*)(Pf + ((rt * 4 + ks) * 64 + lane) * 8);
#pragma unroll
      for (int cj = 0; cj < 2; cj++) {
        short8 bb = *(const short8*)(Vs + ((w * 2 + cj) * 16 + arow) * LVK +
                                     ks * 32 + koff);
#pragma unroll
        for (int rt = 0; rt < 4; rt++)
          acc[rt][cj] = mfma16(a[rt], bb, acc[rt][cj]);
      }
    }
  }
  __syncthreads();
  red[lane][w] = lp;
  __syncthreads();
  if (tid < 64)
    linv[tid] = 1.f / (red[tid][0] + red[tid][1] + red[tid][2] + red[tid][3]);
  __syncthreads();
  int crow0 = (lane >> 4) * 4;
  int hd = bh & 7;
#pragma unroll
  for (int rt = 0; rt < 4; rt++)
#pragma unroll
    for (int cj = 0; cj < 2; cj++) {
      int fcol = (w * 2 + cj) * 16 + arow;
#pragma unroll
      for (int rr = 0; rr < 4; rr++) {
        int nrow = rt * 16 + crow0 + rr;
        float v = acc[rt][cj][rr] * linv[nrow];
        v = v > 0.f ? v : __expf(v) - 1.f;  // ELU
        P.multi[((size_t)(b * N + n0 + nrow)) * (H * F) + hd * F + fcol] =
            f2bf(v);
      }
    }
}

// ====== out projection: hsT[b][f_out][n] = WoT.multi^T, 32x32 tiles ========
// grid 512: b = bid&7 (all blocks reading multi[b] share an XCD)
__global__ __launch_bounds__(256) void g_proj_out(KParams P, int l) {
  constexpr int LK = 136;
  __shared__ short As[32 * LK];
  __shared__ short Bs[32 * LK];
  const short* WoT = P.WoT + (size_t)l * H * F * F;
  const float* ao = P.a_out + (size_t)l * 2 * F;
  float* s1 = P.sA + (size_t)l * 73728 + 65536;
  float* s2 = s1 + 4096;
  int bid = blockIdx.x, tid = threadIdx.x;
  int b = bid & 7, nt = (bid >> 3) & 15, ft = bid >> 7;
  int f0 = ft * 32, nb = nt * 32;
  int lane = tid & 63, w = tid >> 6;
  int rt = w & 1, ct = w >> 1;
  int arow = lane & 15, koff = (lane >> 4) * 8;
  const int KT = H * F;  // 1024
  f32x4 acc = {};
  for (int k0 = 0; k0 < KT; k0 += 128) {
    __syncthreads();
    {
      int r = tid >> 3, e = tid & 7;
      const uint4* gp = (const uint4*)(WoT + (size_t)(f0 + r) * KT + k0) + e * 2;
      uint4* lp = (uint4*)(As + r * LK) + e * 2;
      lp[0] = gp[0]; lp[1] = gp[1];
    }
    {
      int r = tid >> 3, e = tid & 7;
      const uint4* gp =
          (const uint4*)(P.multi + (size_t)(b * N + nb + r) * KT + k0) + e * 2;
      uint4* lp = (uint4*)(Bs + r * LK) + e * 2;
      lp[0] = gp[0]; lp[1] = gp[1];
    }
    __syncthreads();
#pragma unroll
    for (int ks = 0; ks < 4; ks++) {
      short8 a = *(const short8*)(As + (rt * 16 + arow) * LK + ks * 32 + koff);
      short8 bb = *(const short8*)(Bs + (ct * 16 + arow) * LK + ks * 32 + koff);
      acc = mfma16(a, bb, acc);
    }
  }
  int crow0 = (lane >> 4) * 4;
  short* op = P.hsT + (size_t)b * F * N;
#pragma unroll
  for (int r = 0; r < 4; r++)
    op[(size_t)(f0 + rt * 16 + crow0 + r) * N + nb + ct * 16 + arow] =
        f2bf(acc[r]);
  float pa1 = 0.f, pa2 = 0.f;
  {
    int fo = f0 + rt * 16 + crow0;
#pragma unroll
    for (int r = 0; r < 4; r++) {
      pa1 = fmaf(ao[fo + r], acc[r], pa1);
      pa2 = fmaf(ao[F + fo + r], acc[r], pa2);
    }
  }
  pa1 += __shfl_xor(pa1, 16); pa1 += __shfl_xor(pa1, 32);
  pa2 += __shfl_xor(pa2, 16); pa2 += __shfl_xor(pa2, 32);
  if (lane < 16) {
    int n = nb + ct * 16 + lane;
    atomicAdd(&s1[(size_t)b * N + n], pa1);
    atomicAdd(&s2[(size_t)b * N + n], pa2);
  }
}

// ====== single-head attention + residual + LayerNorm (+relu / d_out) ======
// grid 256: b = bid&7 (hsT[b] pinned to XCD b)
__global__ __launch_bounds__(256) void g_attn_single(KParams P, int l) {
  constexpr int LVK = 136;
  __shared__ short Vs[128 * LVK];
  __shared__ short Pf[4 * 64 * 8];
  __shared__ float s2all[512];
  __shared__ float Ot[16][132];
  __shared__ float redS[16][16], redQ[16][16];
  __shared__ float s1r[16], mrow[16], linv[16], muA[16], rsA[16];
  const float* s1g = P.sA + (size_t)l * 73728 + 65536;
  const float* s2g = s1g + 4096;
  const float* lng = P.ln_g + (size_t)l * F;
  const float* lnb = P.ln_b + (size_t)l * F;
  int last = l == 1;
  int bid = blockIdx.x, tid = threadIdx.x;
  int b = bid & 7, nt = bid >> 3;
  int n0 = nt * 16;
  int lane = tid & 63, w = tid >> 6;
  s2all[tid] = s2g[(size_t)b * N + tid];
  s2all[tid + 256] = s2g[(size_t)b * N + tid + 256];
  if (tid < 16) s1r[tid] = s1g[(size_t)b * N + n0 + tid];
  const short* Vg = P.hsT + (size_t)b * F * N;
  int fr = tid >> 1, hf = tid & 1;
  uint4 vreg[8];
  {  // prologue chunk-0 V loads
    const uint4* g4 = (const uint4*)(Vg + (size_t)fr * N + 0 + hf * 64);
#pragma unroll
    for (int k = 0; k < 8; k++) vreg[k] = g4[k];
  }
  __syncthreads();
  {  // prepass masked max
    int r = tid & 15, seg = tid >> 4;
    unsigned long long mb = P.amask[((size_t)(b * N + n0 + r)) * 8 + (seg >> 1)];
    unsigned bits = (unsigned)(mb >> ((seg & 1) * 32));
    float mx = FLOW;
#pragma unroll
    for (int k = 0; k < 32; k++)
      mx = ((bits >> k) & 1u) ? fmaxf(mx, s2all[seg * 32 + k]) : mx;
    redS[r][seg] = mx;
  }
  __syncthreads();
  if (tid < 16) {
    float m2 = FLOW;
#pragma unroll
    for (int k = 0; k < 16; k++) m2 = fmaxf(m2, redS[tid][k]);
    float xm = s1r[tid] + m2;
    mrow[tid] = xm > 0.f ? xm : ALPHA_LR * xm;
  }
  float lp = 0.f;
  int arow = lane & 15, koff = (lane >> 4) * 8;
  int pr = tid & 15, pq = (tid >> 4) & 3;
  f32x4 acc[2] = {};
  const unsigned long long* mp = P.amask + ((size_t)(b * N + n0 + pr)) * 8;
  for (int mc = 0; mc < 4; mc++) {
    int m0 = mc * 128;
    __syncthreads();  // A
    {  // store prefetched V chunk
      uint4* l4 = (uint4*)(Vs + fr * LVK + hf * 64);
#pragma unroll
      for (int k = 0; k < 8; k++) l4[k] = vreg[k];
    }
    {
      float s1v = s1r[pr], mr = mrow[pr];
      unsigned bits = (unsigned)(mp[mc * 2 + (w >> 1)] >> ((w & 1) * 32));
      short8 pk;
#pragma unroll
      for (int j = 0; j < 8; j++) {
        float xv = s1v + s2all[m0 + w * 32 + pq * 8 + j];
        xv = xv > 0.f ? xv : ALPHA_LR * xv;
        float p = __expf(xv - mr);
        p = ((bits >> (pq * 8 + j)) & 1u) ? p : 0.f;
        lp += p;
        pk[j] = f2bf(p);
      }
      *(short8*)(Pf + (w * 64 + ((pq << 4) | pr)) * 8) = pk;
    }
    __syncthreads();  // B
    if (mc < 3) {  // next chunk loads overlap MFMA
      const uint4* g4 = (const uint4*)(Vg + (size_t)fr * N + (m0 + 128) + hf * 64);
#pragma unroll
      for (int k = 0; k < 8; k++) vreg[k] = g4[k];
    }
#pragma unroll
    for (int ks = 0; ks < 4; ks++) {
      short8 a = *(const short8*)(Pf + (ks * 64 + lane) * 8);
#pragma unroll
      for (int cj = 0; cj < 2; cj++) {
        short8 bb = *(const short8*)(Vs + ((w * 2 + cj) * 16 + arow) * LVK +
                                     ks * 32 + koff);
        acc[cj] = mfma16(a, bb, acc[cj]);
      }
    }
  }
  __syncthreads();
  redS[pr][tid >> 4] = lp;
  __syncthreads();
  if (tid < 16) {
    float lsum = 0.f;
#pragma unroll
    for (int k = 0; k < 16; k++) lsum += redS[tid][k];
    linv[tid] = 1.f / lsum;
  }
  __syncthreads();
  int crow0 = (lane >> 4) * 4;
#pragma unroll
  for (int cj = 0; cj < 2; cj++) {
    int fcol = (w * 2 + cj) * 16 + arow;
#pragma unroll
    for (int rr = 0; rr < 4; rr++) {
      int row = crow0 + rr;
      Ot[row][fcol] = acc[cj][rr] * linv[row];
    }
  }
  __syncthreads();
  int r2 = tid >> 4, f8 = (tid & 15) * 8;
  size_t gbase = ((size_t)(b * N + n0 + r2)) * F + f8;
  float v[8];
  float s = 0.f, sq = 0.f;
#pragma unroll
  for (int j = 0; j < 8; j++) {
    float t = Ot[r2][f8 + j] + P.h[gbase + j];
    v[j] = t;
    s += t;
    sq = fmaf(t, t, sq);
  }
  redS[r2][tid & 15] = s;
  redQ[r2][tid & 15] = sq;
  __syncthreads();
  if (tid < 16) {
    float ss = 0.f, qq = 0.f;
#pragma unroll
    for (int k = 0; k < 16; k++) { ss += redS[tid][k]; qq += redQ[tid][k]; }
    float mu = ss * (1.f / F);
    muA[tid] = mu;
    rsA[tid] = rsqrtf(qq * (1.f / F) - mu * mu + EPS_LN);
  }
  __syncthreads();
  float mu = muA[r2], rs = rsA[r2];
#pragma unroll
  for (int j = 0; j < 8; j++) {
    float y = (v[j] - mu) * rs * lng[f8 + j] + lnb[f8 + j];
    if (last) {
      P.dout[gbase + j] = y;
    } else {
      y = fmaxf(y, 0.f);
      P.h[gbase + j] = y;
      P.hb[gbase + j] = f2bf(y);
    }
  }
}

extern "C" void kernel_launch(void* const* d_in, const int* in_sizes, int n_in,
                              void* d_out, int out_size, void* d_ws,
                              size_t ws_size, hipStream_t stream) {
  char* p = (char*)d_ws;
  auto alloc = [&](size_t bytes) {
    char* r = p;
    p += (bytes + 255) & ~(size_t)255;
    return r;
  };
  KParams P;
  P.x = (const float*)d_in[0];
  P.adj = (const int*)d_in[1];
  P.Wp = (const float*)d_in[2];
  P.bp = (const float*)d_in[3];
  P.W_heads = (const float*)d_in[4];
  P.a_heads = (const float*)d_in[5];
  P.W_out = (const float*)d_in[6];
  P.a_out = (const float*)d_in[7];
  P.ln_g = (const float*)d_in[8];
  P.ln_b = (const float*)d_in[9];
  P.sA = (float*)alloc((size_t)2 * 73728 * 4);
  P.WTh = (short*)alloc((size_t)2 * H * F * F * 2);
  P.WoT = (short*)alloc((size_t)2 * H * F * F * 2);
  P.amask = (unsigned long long*)alloc((size_t)BN * 8 * 8);
  P.h = (float*)alloc((size_t)BN * F * 4);
  P.hb = (short*)alloc((size_t)BN * F * 2);
  P.hhT = (short*)alloc((size_t)B * H * F * N * 2);
  P.multi = (short*)alloc((size_t)BN * H * F * 2);
  P.hsT = (short*)alloc((size_t)B * F * N * 2);
  P.dout = (float*)d_out;

  g_setup<<<512, 256, 0, stream>>>(P);
  for (int l = 0; l < 2; l++) {
    g_proj_heads<<<512, 256, 0, stream>>>(P, l);
    g_attn_heads<<<512, 256, 0, stream>>>(P, l);
    g_proj_out<<<512, 256, 0, stream>>>(P, l);
    g_attn_single<<<256, 256, 0, stream>>>(P, l);
  }
}

// Round 7
// 184.388 us; speedup vs baseline: 1.2654x; 1.2654x over previous
//
#include <hip/hip_runtime.h>

// GAT spatio-temporal model — bf16 MFMA, R3 structure + XCD-aware swizzle in
// attention kernels + memset folded into setup.
// B=8, N=512, Din=64, H=8, F=128, L=2.

constexpr int B = 8, N = 512, DIN = 64, H = 8, F = 128;
constexpr int BN = B * N;          // 4096
constexpr float ALPHA_LR = 0.2f;   // LeakyReLU slope
constexpr float EPS_LN = 1e-5f;
constexpr float FLOW = -3.0e38f;   // "-inf" substitute

typedef __attribute__((ext_vector_type(8))) short short8;  // 8 bf16
typedef __attribute__((ext_vector_type(4))) float f32x4;

__device__ __forceinline__ f32x4 mfma16(short8 a, short8 b, f32x4 c) {
  return __builtin_amdgcn_mfma_f32_16x16x32_bf16(a, b, c, 0, 0, 0);
}

__device__ __forceinline__ short f2bf(float f) {  // RNE f32 -> bf16 bits
  union { float f; unsigned u; } v;
  v.f = f;
  unsigned r = v.u + 0x7FFFu + ((v.u >> 16) & 1u);
  return (short)(r >> 16);
}

// ========== setup: zero sA | adjmask | proj_in | weight transposes ========
// grid 512 x 256
__global__ __launch_bounds__(256) void g_setup(
    const float* __restrict__ x, const int* __restrict__ adj,
    const float* __restrict__ Wp, const float* __restrict__ bp,
    const float* __restrict__ W_heads, const float* __restrict__ W_out,
    float* __restrict__ h, short* __restrict__ hb,
    unsigned long long* __restrict__ amask, short* __restrict__ WTh,
    short* __restrict__ WoT, float* __restrict__ sA) {
  __shared__ float T[32][33];
  __shared__ float xr[2][64];
  int bid = blockIdx.x, tid = threadIdx.x;
  for (int i = tid; i < 288; i += 256) sA[(size_t)bid * 288 + i] = 0.f;
  {  // adjacency -> 64-bit masks (batched loads)
    int lane = tid & 63, wv = tid >> 6;
    int v[16];
#pragma unroll
    for (int j = 0; j < 16; j++) {
      int w = (bid + j * 512) * 4 + wv;
      v[j] = adj[(size_t)w * 64 + lane];
    }
#pragma unroll
    for (int j = 0; j < 16; j++) {
      int w = (bid + j * 512) * 4 + wv;
      unsigned long long m = __ballot(v[j] > 0);
      if (lane == 0) amask[w] = m;
    }
  }
  {  // input projection: h = relu(x@Wp+bp), 2 rows per unit
    int half = tid >> 7, f = tid & 127;
    for (int u = bid; u < 2048; u += 512) {
      int row = u * 2 + half;
      __syncthreads();
      if (f < 64) xr[half][f] = x[(size_t)row * DIN + f];
      __syncthreads();
      float acc = bp[f];
#pragma unroll
      for (int i = 0; i < DIN; i++)
        acc = fmaf(xr[half][i], Wp[i * F + f], acc);
      acc = fmaxf(acc, 0.f);
      h[(size_t)row * F + f] = acc;
      hb[(size_t)row * F + f] = f2bf(acc);
    }
  }
  {  // weight transposes f32 [bt][R][C] -> bf16 [bt][C][R], one 32x32 tile
    const float* in; short* out; int R, C, bx, by, bt;
    if (bid < 256) {
      in = W_heads; out = WTh; R = 128; C = 128;
      bx = bid & 3; by = (bid >> 2) & 3; bt = bid >> 4;
    } else {
      int i = bid - 256;
      in = W_out; out = WoT; R = 1024; C = 128;
      bx = i & 3; by = (i >> 2) & 31; bt = i >> 7;
    }
    int c0 = bx * 32, r0 = by * 32;
    const float* ip = in + (size_t)bt * R * C;
    short* op = out + (size_t)bt * R * C;
    __syncthreads();
    {
      int r = tid >> 3, c4 = (tid & 7) * 4;
      float4 v = *(const float4*)(ip + (size_t)(r0 + r) * C + c0 + c4);
      T[r][c4] = v.x; T[r][c4 + 1] = v.y; T[r][c4 + 2] = v.z; T[r][c4 + 3] = v.w;
    }
    __syncthreads();
    {
      int cr = tid >> 3, q = (tid & 7) * 4;
      short4 o;
      o.x = f2bf(T[q][cr]); o.y = f2bf(T[q + 1][cr]);
      o.z = f2bf(T[q + 2][cr]); o.w = f2bf(T[q + 3][cr]);
      *(short4*)(op + (size_t)(c0 + cr) * R + r0 + q) = o;
    }
  }
}

// ========= head projection: hhT[bh][f_out][n] = WT[h] . hb^T, + s1/s2 =====
// grid (N/128, 2, B*H), block 256.  (R3-exact)
__global__ __launch_bounds__(256) void k_proj_heads_mfma(
    const short* __restrict__ WT, const short* __restrict__ hb,
    const float* __restrict__ ah_base, short* __restrict__ hhT,
    float* __restrict__ s1, float* __restrict__ s2) {
  int n0 = blockIdx.x * 128;
  int ft = blockIdx.y;
  int bh = blockIdx.z;
  int b = bh >> 3, hd = bh & 7;
  constexpr int LK = 136;
  __shared__ short As[64 * LK];
  __shared__ short Bs[128 * LK];
  int tid = threadIdx.x, lane = tid & 63, w = tid >> 6;
  {  // stage A: 64 rows x 256B
    int r = tid >> 2, q = tid & 3;
    const uint4* g = (const uint4*)(WT + ((size_t)hd * F + ft * 64 + r) * F) + q * 4;
    uint4* lp = (uint4*)(As + r * LK) + q * 4;
    lp[0] = g[0]; lp[1] = g[1]; lp[2] = g[2]; lp[3] = g[3];
  }
  {  // stage B: 128 rows x 256B
    int q = tid & 3;
    for (int r = tid >> 2; r < 128; r += 64) {
      const uint4* g = (const uint4*)(hb + ((size_t)(b * N + n0 + r)) * F) + q * 4;
      uint4* lp = (uint4*)(Bs + r * LK) + q * 4;
      lp[0] = g[0]; lp[1] = g[1]; lp[2] = g[2]; lp[3] = g[3];
    }
  }
  __syncthreads();
  int arow = lane & 15, koff = (lane >> 4) * 8;
  f32x4 acc[4][2] = {};
#pragma unroll
  for (int ks = 0; ks < 4; ks++) {
    short8 a[4], bb[2];
#pragma unroll
    for (int rt = 0; rt < 4; rt++)
      a[rt] = *(const short8*)(As + (rt * 16 + arow) * LK + ks * 32 + koff);
#pragma unroll
    for (int cj = 0; cj < 2; cj++)
      bb[cj] = *(const short8*)(Bs + ((2 * w + cj) * 16 + arow) * LK + ks * 32 + koff);
#pragma unroll
    for (int rt = 0; rt < 4; rt++)
#pragma unroll
      for (int cj = 0; cj < 2; cj++)
        acc[rt][cj] = mfma16(a[rt], bb[cj], acc[rt][cj]);
  }
  short* outp = hhT + (size_t)bh * F * N;
  int crow0 = (lane >> 4) * 4;
#pragma unroll
  for (int rt = 0; rt < 4; rt++)
#pragma unroll
    for (int cj = 0; cj < 2; cj++) {
      int fo = ft * 64 + rt * 16 + crow0;
      int n = n0 + (2 * w + cj) * 16 + arow;
#pragma unroll
      for (int r = 0; r < 4; r++)
        outp[(size_t)(fo + r) * N + n] = f2bf(acc[rt][cj][r]);
    }
  // fused s1/s2 epilogue
  const float* ah = ah_base + (size_t)hd * 2 * F;
  float pa1[2] = {0.f, 0.f}, pa2[2] = {0.f, 0.f};
#pragma unroll
  for (int rt = 0; rt < 4; rt++) {
    int fo = ft * 64 + rt * 16 + crow0;
#pragma unroll
    for (int r = 0; r < 4; r++) {
      float a1v = ah[fo + r], a2v = ah[F + fo + r];
      pa1[0] = fmaf(a1v, acc[rt][0][r], pa1[0]);
      pa1[1] = fmaf(a1v, acc[rt][1][r], pa1[1]);
      pa2[0] = fmaf(a2v, acc[rt][0][r], pa2[0]);
      pa2[1] = fmaf(a2v, acc[rt][1][r], pa2[1]);
    }
  }
#pragma unroll
  for (int cj = 0; cj < 2; cj++) {
    float v1 = pa1[cj], v2 = pa2[cj];
    v1 += __shfl_xor(v1, 16); v1 += __shfl_xor(v1, 32);
    v2 += __shfl_xor(v2, 16); v2 += __shfl_xor(v2, 32);
    if (lane < 16) {
      int n = n0 + (2 * w + cj) * 16 + lane;
      atomicAdd(&s1[(size_t)bh * N + n], v1);
      atomicAdd(&s2[(size_t)bh * N + n], v2);
    }
  }
}

// ========= fused attention, 8 heads, single-pass softmax, ELU epilogue ====
// grid 512 flat, XCD swizzle: bh = bid&63 (same-bh blocks -> same XCD).
__global__ __launch_bounds__(256) void k_attn_heads3(
    const short* __restrict__ VT, const float* __restrict__ s1g,
    const float* __restrict__ s2g, const unsigned long long* __restrict__ amask,
    short* __restrict__ multi) {
  int bid = blockIdx.x;
  int bh = bid & 63, nt = bid >> 6;
  int b = bh >> 3, hd = bh & 7;
  int n0 = nt * 64;
  constexpr int LVK = 136;
  __shared__ short Vs[128 * LVK];
  __shared__ short Pf[16 * 64 * 8];
  __shared__ float s2all[512];
  __shared__ float s1r[64], mrow[64], linv[64];
  __shared__ float red[64][4];

  int tid = threadIdx.x, lane = tid & 63, w = tid >> 6;
  s2all[tid] = s2g[(size_t)bh * N + tid];
  s2all[tid + 256] = s2g[(size_t)bh * N + tid + 256];
  if (tid < 64) s1r[tid] = s1g[(size_t)bh * N + n0 + tid];
  __syncthreads();
  {  // prepass: per-row masked max of s2 (LeakyReLU monotone)
    const unsigned long long* mq = amask + ((size_t)(b * N + n0 + lane)) * 8;
    float mx = FLOW;
#pragma unroll
    for (int j = 0; j < 2; j++) {
      unsigned long long mb = mq[w * 2 + j];
      int base = w * 128 + j * 64;
      unsigned lo = (unsigned)mb, hi = (unsigned)(mb >> 32);
#pragma unroll
      for (int k = 0; k < 32; k++) {
        mx = ((lo >> k) & 1u) ? fmaxf(mx, s2all[base + k]) : mx;
        mx = ((hi >> k) & 1u) ? fmaxf(mx, s2all[base + 32 + k]) : mx;
      }
    }
    red[lane][w] = mx;
  }
  __syncthreads();
  if (tid < 64) {
    float m2 = fmaxf(fmaxf(red[tid][0], red[tid][1]),
                     fmaxf(red[tid][2], red[tid][3]));
    float xm = s1r[tid] + m2;
    mrow[tid] = xm > 0.f ? xm : ALPHA_LR * xm;
  }
  float lp = 0.f;
  int arow = lane & 15, koff = (lane >> 4) * 8;
  f32x4 acc[4][2] = {};
  const short* Vg = VT + (size_t)bh * F * N;
  const unsigned long long* mp = amask + ((size_t)(b * N + n0 + lane)) * 8;
  for (int mc = 0; mc < 4; mc++) {
    int m0 = mc * 128;
    __syncthreads();  // prior MFMA done with Vs/Pf
    {                 // stage V^T chunk: 128 f x 128 m
      int fr = tid >> 1, hf = tid & 1;
      const uint4* g4 = (const uint4*)(Vg + (size_t)fr * N + m0 + hf * 64);
      uint4* l4 = (uint4*)(Vs + fr * LVK + hf * 64);
#pragma unroll
      for (int k = 0; k < 8; k++) l4[k] = g4[k];
    }
    {  // P: row = lane, k-range = w*32..+32, A-fragment order
      float s1v = s1r[lane], mr = mrow[lane];
      unsigned bits = (unsigned)(mp[mc * 2 + (w >> 1)] >> ((w & 1) * 32));
      short* pbase = Pf + (((lane >> 4) * 4 + w) * 64) * 8;
#pragma unroll
      for (int q = 0; q < 4; q++) {
        short8 pk;
#pragma unroll
        for (int j = 0; j < 8; j++) {
          float xv = s1v + s2all[m0 + w * 32 + q * 8 + j];
          xv = xv > 0.f ? xv : ALPHA_LR * xv;
          float p = __expf(xv - mr);
          p = ((bits >> (q * 8 + j)) & 1u) ? p : 0.f;
          lp += p;
          pk[j] = f2bf(p);
        }
        *(short8*)(pbase + ((q << 4) | (lane & 15)) * 8) = pk;
      }
    }
    __syncthreads();
#pragma unroll
    for (int ks = 0; ks < 4; ks++) {
      short8 a[4];
#pragma unroll
      for (int rt = 0; rt < 4; rt++)
        a[rt] = *(const short8*)(Pf + ((rt * 4 + ks) * 64 + lane) * 8);
#pragma unroll
      for (int cj = 0; cj < 2; cj++) {
        short8 bb = *(const short8*)(Vs + ((w * 2 + cj) * 16 + arow) * LVK +
                                     ks * 32 + koff);
#pragma unroll
        for (int rt = 0; rt < 4; rt++)
          acc[rt][cj] = mfma16(a[rt], bb, acc[rt][cj]);
      }
    }
  }
  __syncthreads();
  red[lane][w] = lp;
  __syncthreads();
  if (tid < 64)
    linv[tid] = 1.f / (red[tid][0] + red[tid][1] + red[tid][2] + red[tid][3]);
  __syncthreads();
  int crow0 = (lane >> 4) * 4;
#pragma unroll
  for (int rt = 0; rt < 4; rt++)
#pragma unroll
    for (int cj = 0; cj < 2; cj++) {
      int fcol = (w * 2 + cj) * 16 + arow;
#pragma unroll
      for (int rr = 0; rr < 4; rr++) {
        int nrow = rt * 16 + crow0 + rr;
        float v = acc[rt][cj][rr] * linv[nrow];
        v = v > 0.f ? v : __expf(v) - 1.f;  // ELU
        multi[((size_t)(b * N + n0 + nrow)) * (H * F) + hd * F + fcol] = f2bf(v);
      }
    }
}

// ========= out projection: hsT[b][f_out][n] = WoT . multi^T, + s1/s2 ======
// grid (4, 8, B), block 256. Tile 32 f_out x 64 n, K=1024.  (R3-exact)
__global__ __launch_bounds__(256) void k_proj_out_mfma(
    const short* __restrict__ WoT, const short* __restrict__ multi,
    const float* __restrict__ ao, short* __restrict__ hsT,
    float* __restrict__ s1, float* __restrict__ s2) {
  int ft = blockIdx.x, nt = blockIdx.y, b = blockIdx.z;
  constexpr int LK = 136;
  __shared__ short As[32 * LK];
  __shared__ short Bs[64 * LK];
  int tid = threadIdx.x, lane = tid & 63, w = tid >> 6;
  int arow = lane & 15, koff = (lane >> 4) * 8;
  const int KT = H * F;  // 1024
  f32x4 acc[2] = {};
  for (int k0 = 0; k0 < KT; k0 += 128) {
    __syncthreads();
    {  // A: 32 rows x 128 k
      int r = tid >> 3, e = tid & 7;
      const uint4* gp = (const uint4*)(WoT + (size_t)(ft * 32 + r) * KT + k0) + e * 2;
      uint4* lp = (uint4*)(As + r * LK) + e * 2;
      lp[0] = gp[0]; lp[1] = gp[1];
    }
    {  // B: 64 rows x 128 k
      int r = tid >> 2, q = tid & 3;
      const uint4* gp =
          (const uint4*)(multi + (size_t)(b * N + nt * 64 + r) * KT + k0) + q * 4;
      uint4* lp = (uint4*)(Bs + r * LK) + q * 4;
      lp[0] = gp[0]; lp[1] = gp[1]; lp[2] = gp[2]; lp[3] = gp[3];
    }
    __syncthreads();
#pragma unroll
    for (int ks = 0; ks < 4; ks++) {
      short8 b0 = *(const short8*)(Bs + (w * 16 + arow) * LK + ks * 32 + koff);
      short8 a0 = *(const short8*)(As + arow * LK + ks * 32 + koff);
      short8 a1 = *(const short8*)(As + (16 + arow) * LK + ks * 32 + koff);
      acc[0] = mfma16(a0, b0, acc[0]);
      acc[1] = mfma16(a1, b0, acc[1]);
    }
  }
  int crow0 = (lane >> 4) * 4;
  short* op = hsT + (size_t)b * F * N;
#pragma unroll
  for (int rt = 0; rt < 2; rt++)
#pragma unroll
    for (int r = 0; r < 4; r++)
      op[(size_t)(ft * 32 + rt * 16 + crow0 + r) * N + nt * 64 + w * 16 + arow] =
          f2bf(acc[rt][r]);
  float pa1 = 0.f, pa2 = 0.f;
#pragma unroll
  for (int rt = 0; rt < 2; rt++) {
    int fo = ft * 32 + rt * 16 + crow0;
#pragma unroll
    for (int r = 0; r < 4; r++) {
      pa1 = fmaf(ao[fo + r], acc[rt][r], pa1);
      pa2 = fmaf(ao[F + fo + r], acc[rt][r], pa2);
    }
  }
  pa1 += __shfl_xor(pa1, 16); pa1 += __shfl_xor(pa1, 32);
  pa2 += __shfl_xor(pa2, 16); pa2 += __shfl_xor(pa2, 32);
  if (lane < 16) {
    int n = nt * 64 + w * 16 + lane;
    atomicAdd(&s1[(size_t)b * N + n], pa1);
    atomicAdd(&s2[(size_t)b * N + n], pa2);
  }
}

// ========= fused attention single head + residual + LayerNorm =============
// grid 256 flat, XCD swizzle: b = bid&7 (same-b blocks -> same XCD).
template <int LAST>
__global__ __launch_bounds__(256) void k_attn_single3(
    const short* __restrict__ VT, const float* __restrict__ s1g,
    const float* __restrict__ s2g, const unsigned long long* __restrict__ amask,
    const float* __restrict__ resid, const float* __restrict__ lng,
    const float* __restrict__ lnb, float* __restrict__ hout,
    short* __restrict__ hbout, float* __restrict__ dout) {
  int bid = blockIdx.x;
  int b = bid & 7, nt = bid >> 3;
  int n0 = nt * 16;
  constexpr int LVK = 136;
  __shared__ short Vs[128 * LVK];
  __shared__ short Pf[4 * 64 * 8];
  __shared__ float s2all[512];
  __shared__ float Ot[16][132];
  __shared__ float redS[16][16], redQ[16][16];
  __shared__ float s1r[16], mrow[16], linv[16], muA[16], rsA[16];

  int tid = threadIdx.x, lane = tid & 63, w = tid >> 6;
  s2all[tid] = s2g[(size_t)b * N + tid];
  s2all[tid + 256] = s2g[(size_t)b * N + tid + 256];
  if (tid < 16) s1r[tid] = s1g[(size_t)b * N + n0 + tid];
  __syncthreads();
  {  // prepass masked max: r = tid&15, seg = tid>>4 covers m [seg*32,+32)
    int r = tid & 15, seg = tid >> 4;
    unsigned long long mb = amask[((size_t)(b * N + n0 + r)) * 8 + (seg >> 1)];
    unsigned bits = (unsigned)(mb >> ((seg & 1) * 32));
    float mx = FLOW;
#pragma unroll
    for (int k = 0; k < 32; k++)
      mx = ((bits >> k) & 1u) ? fmaxf(mx, s2all[seg * 32 + k]) : mx;
    redS[r][seg] = mx;
  }
  __syncthreads();
  if (tid < 16) {
    float m2 = FLOW;
#pragma unroll
    for (int k = 0; k < 16; k++) m2 = fmaxf(m2, redS[tid][k]);
    float xm = s1r[tid] + m2;
    mrow[tid] = xm > 0.f ? xm : ALPHA_LR * xm;
  }
  float lp = 0.f;
  int arow = lane & 15, koff = (lane >> 4) * 8;
  int pr = tid & 15, pq = (tid >> 4) & 3;
  f32x4 acc[2] = {};
  const short* Vg = VT + (size_t)b * F * N;
  const unsigned long long* mp = amask + ((size_t)(b * N + n0 + pr)) * 8;
  for (int mc = 0; mc < 4; mc++) {
    int m0 = mc * 128;
    __syncthreads();
    {  // stage V^T chunk
      int fr = tid >> 1, hf = tid & 1;
      const uint4* g4 = (const uint4*)(Vg + (size_t)fr * N + m0 + hf * 64);
      uint4* l4 = (uint4*)(Vs + fr * LVK + hf * 64);
#pragma unroll
      for (int k = 0; k < 8; k++) l4[k] = g4[k];
    }
    {  // P: row pr, k = w*32 + pq*8 + j
      float s1v = s1r[pr], mr = mrow[pr];
      unsigned bits = (unsigned)(mp[mc * 2 + (w >> 1)] >> ((w & 1) * 32));
      short8 pk;
#pragma unroll
      for (int j = 0; j < 8; j++) {
        float xv = s1v + s2all[m0 + w * 32 + pq * 8 + j];
        xv = xv > 0.f ? xv : ALPHA_LR * xv;
        float p = __expf(xv - mr);
        p = ((bits >> (pq * 8 + j)) & 1u) ? p : 0.f;
        lp += p;
        pk[j] = f2bf(p);
      }
      *(short8*)(Pf + (w * 64 + ((pq << 4) | pr)) * 8) = pk;
    }
    __syncthreads();
#pragma unroll
    for (int ks = 0; ks < 4; ks++) {
      short8 a = *(const short8*)(Pf + (ks * 64 + lane) * 8);
#pragma unroll
      for (int cj = 0; cj < 2; cj++) {
        short8 bb = *(const short8*)(Vs + ((w * 2 + cj) * 16 + arow) * LVK +
                                     ks * 32 + koff);
        acc[cj] = mfma16(a, bb, acc[cj]);
      }
    }
  }
  __syncthreads();
  redS[pr][tid >> 4] = lp;
  __syncthreads();
  if (tid < 16) {
    float l = 0.f;
#pragma unroll
    for (int k = 0; k < 16; k++) l += redS[tid][k];
    linv[tid] = 1.f / l;
  }
  __syncthreads();
  int crow0 = (lane >> 4) * 4;
#pragma unroll
  for (int cj = 0; cj < 2; cj++) {
    int fcol = (w * 2 + cj) * 16 + arow;
#pragma unroll
    for (int rr = 0; rr < 4; rr++) {
      int row = crow0 + rr;
      Ot[row][fcol] = acc[cj][rr] * linv[row];
    }
  }
  __syncthreads();
  int r2 = tid >> 4, f8 = (tid & 15) * 8;
  size_t gbase = ((size_t)(b * N + n0 + r2)) * F + f8;
  float v[8];
  float s = 0.f, sq = 0.f;
#pragma unroll
  for (int j = 0; j < 8; j++) {
    float t = Ot[r2][f8 + j] + resid[gbase + j];
    v[j] = t;
    s += t;
    sq = fmaf(t, t, sq);
  }
  redS[r2][tid & 15] = s;
  redQ[r2][tid & 15] = sq;
  __syncthreads();
  if (tid < 16) {
    float ss = 0.f, qq = 0.f;
#pragma unroll
    for (int k = 0; k < 16; k++) { ss += redS[tid][k]; qq += redQ[tid][k]; }
    float mu = ss * (1.f / F);
    muA[tid] = mu;
    rsA[tid] = rsqrtf(qq * (1.f / F) - mu * mu + EPS_LN);
  }
  __syncthreads();
  float mu = muA[r2], rs = rsA[r2];
#pragma unroll
  for (int j = 0; j < 8; j++) {
    float y = (v[j] - mu) * rs * lng[f8 + j] + lnb[f8 + j];
    if (LAST) {
      dout[gbase + j] = y;
    } else {
      y = fmaxf(y, 0.f);
      hout[gbase + j] = y;
      hbout[gbase + j] = f2bf(y);
    }
  }
}

extern "C" void kernel_launch(void* const* d_in, const int* in_sizes, int n_in,
                              void* d_out, int out_size, void* d_ws,
                              size_t ws_size, hipStream_t stream) {
  const float* x = (const float*)d_in[0];
  const int* adj = (const int*)d_in[1];
  const float* Wp = (const float*)d_in[2];
  const float* bp = (const float*)d_in[3];
  const float* W_heads = (const float*)d_in[4];
  const float* a_heads = (const float*)d_in[5];
  const float* W_out = (const float*)d_in[6];
  const float* a_out = (const float*)d_in[7];
  const float* ln_g = (const float*)d_in[8];
  const float* ln_b = (const float*)d_in[9];

  char* p = (char*)d_ws;
  auto alloc = [&](size_t bytes) {
    char* r = p;
    p += (bytes + 255) & ~(size_t)255;
    return r;
  };
  float* sA = (float*)alloc((size_t)2 * 73728 * 4);
  short* WTh = (short*)alloc((size_t)2 * H * F * F * 2);
  short* WoT = (short*)alloc((size_t)2 * H * F * F * 2);
  unsigned long long* amask = (unsigned long long*)alloc((size_t)BN * 8 * 8);
  float* h = (float*)alloc((size_t)BN * F * 4);
  short* hb = (short*)alloc((size_t)BN * F * 2);
  short* hhT = (short*)alloc((size_t)B * H * F * N * 2);
  short* multi = (short*)alloc((size_t)BN * H * F * 2);
  short* hsT = (short*)alloc((size_t)B * F * N * 2);

  g_setup<<<512, 256, 0, stream>>>(x, adj, Wp, bp, W_heads, W_out, h, hb,
                                   amask, WTh, WoT, sA);
  for (int l = 0; l < 2; l++) {
    float* s1h = sA + (size_t)l * 73728;
    float* s2h = s1h + 32768;
    float* s1o = s2h + 32768;
    float* s2o = s1o + 4096;
    k_proj_heads_mfma<<<dim3(4, 2, 64), 256, 0, stream>>>(
        WTh + (size_t)l * H * F * F, hb, a_heads + (size_t)l * H * 2 * F, hhT,
        s1h, s2h);
    k_attn_heads3<<<dim3(512), 256, 0, stream>>>(hhT, s1h, s2h, amask, multi);
    k_proj_out_mfma<<<dim3(4, 8, 8), 256, 0, stream>>>(
        WoT + (size_t)l * F * H * F, multi, a_out + (size_t)l * 2 * F, hsT, s1o,
        s2o);
    if (l == 0)
      k_attn_single3<0><<<dim3(256), 256, 0, stream>>>(
          hsT, s1o, s2o, amask, h, ln_g, ln_b, h, hb, nullptr);
    else
      k_attn_single3<1><<<dim3(256), 256, 0, stream>>>(
          hsT, s1o, s2o, amask, h, ln_g + F, ln_b + F, nullptr, nullptr,
          (float*)d_out);
  }
}

// Round 8
// 178.743 us; speedup vs baseline: 1.3053x; 1.0316x over previous
//
#include <hip/hip_runtime.h>

// GAT spatio-temporal model — bf16 MFMA pipeline.
// R8: occupancy push — attn_heads & proj_heads split to 1024 blocks with
// smaller LDS footprints (4 blocks/CU instead of 2).
// B=8, N=512, Din=64, H=8, F=128, L=2.

constexpr int B = 8, N = 512, DIN = 64, H = 8, F = 128;
constexpr int BN = B * N;          // 4096
constexpr float ALPHA_LR = 0.2f;   // LeakyReLU slope
constexpr float EPS_LN = 1e-5f;
constexpr float FLOW = -3.0e38f;   // "-inf" substitute

typedef __attribute__((ext_vector_type(8))) short short8;  // 8 bf16
typedef __attribute__((ext_vector_type(4))) float f32x4;

__device__ __forceinline__ f32x4 mfma16(short8 a, short8 b, f32x4 c) {
  return __builtin_amdgcn_mfma_f32_16x16x32_bf16(a, b, c, 0, 0, 0);
}

__device__ __forceinline__ short f2bf(float f) {  // RNE f32 -> bf16 bits
  union { float f; unsigned u; } v;
  v.f = f;
  unsigned r = v.u + 0x7FFFu + ((v.u >> 16) & 1u);
  return (short)(r >> 16);
}

// ========== setup: zero sA | adjmask | proj_in | weight transposes ========
// grid 512 x 256  (R7-exact)
__global__ __launch_bounds__(256) void g_setup(
    const float* __restrict__ x, const int* __restrict__ adj,
    const float* __restrict__ Wp, const float* __restrict__ bp,
    const float* __restrict__ W_heads, const float* __restrict__ W_out,
    float* __restrict__ h, short* __restrict__ hb,
    unsigned long long* __restrict__ amask, short* __restrict__ WTh,
    short* __restrict__ WoT, float* __restrict__ sA) {
  __shared__ float T[32][33];
  __shared__ float xr[2][64];
  int bid = blockIdx.x, tid = threadIdx.x;
  for (int i = tid; i < 288; i += 256) sA[(size_t)bid * 288 + i] = 0.f;
  {
    int lane = tid & 63, wv = tid >> 6;
    int v[16];
#pragma unroll
    for (int j = 0; j < 16; j++) {
      int w = (bid + j * 512) * 4 + wv;
      v[j] = adj[(size_t)w * 64 + lane];
    }
#pragma unroll
    for (int j = 0; j < 16; j++) {
      int w = (bid + j * 512) * 4 + wv;
      unsigned long long m = __ballot(v[j] > 0);
      if (lane == 0) amask[w] = m;
    }
  }
  {
    int half = tid >> 7, f = tid & 127;
    for (int u = bid; u < 2048; u += 512) {
      int row = u * 2 + half;
      __syncthreads();
      if (f < 64) xr[half][f] = x[(size_t)row * DIN + f];
      __syncthreads();
      float acc = bp[f];
#pragma unroll
      for (int i = 0; i < DIN; i++)
        acc = fmaf(xr[half][i], Wp[i * F + f], acc);
      acc = fmaxf(acc, 0.f);
      h[(size_t)row * F + f] = acc;
      hb[(size_t)row * F + f] = f2bf(acc);
    }
  }
  {
    const float* in; short* out; int R, C, bx, by, bt;
    if (bid < 256) {
      in = W_heads; out = WTh; R = 128; C = 128;
      bx = bid & 3; by = (bid >> 2) & 3; bt = bid >> 4;
    } else {
      int i = bid - 256;
      in = W_out; out = WoT; R = 1024; C = 128;
      bx = i & 3; by = (i >> 2) & 31; bt = i >> 7;
    }
    int c0 = bx * 32, r0 = by * 32;
    const float* ip = in + (size_t)bt * R * C;
    short* op = out + (size_t)bt * R * C;
    __syncthreads();
    {
      int r = tid >> 3, c4 = (tid & 7) * 4;
      float4 v = *(const float4*)(ip + (size_t)(r0 + r) * C + c0 + c4);
      T[r][c4] = v.x; T[r][c4 + 1] = v.y; T[r][c4 + 2] = v.z; T[r][c4 + 3] = v.w;
    }
    __syncthreads();
    {
      int cr = tid >> 3, q = (tid & 7) * 4;
      short4 o;
      o.x = f2bf(T[q][cr]); o.y = f2bf(T[q + 1][cr]);
      o.z = f2bf(T[q + 2][cr]); o.w = f2bf(T[q + 3][cr]);
      *(short4*)(op + (size_t)(c0 + cr) * R + r0 + q) = o;
    }
  }
}

// ========= head projection: hhT[bh][f_out][n] = WT[h] . hb^T, + s1/s2 =====
// grid 1024 flat: nt(8) x ft(2) x bh(64). Tile 64 f_out x 64 n. LDS 35 KB ->
// 4 blocks/CU.
__global__ __launch_bounds__(256) void k_proj_heads_mfma2(
    const short* __restrict__ WT, const short* __restrict__ hb,
    const float* __restrict__ ah_base, short* __restrict__ hhT,
    float* __restrict__ s1, float* __restrict__ s2) {
  int bid = blockIdx.x;
  int nt = bid & 7, ft = (bid >> 3) & 1, bh = bid >> 4;
  int b = bh >> 3, hd = bh & 7;
  int n0 = nt * 64;
  constexpr int LK = 136;
  __shared__ short As[64 * LK];
  __shared__ short Bs[64 * LK];
  int tid = threadIdx.x, lane = tid & 63, w = tid >> 6;
  {  // A: 64 f_out rows x 128 k
    int r = tid >> 2, q = tid & 3;
    const uint4* g = (const uint4*)(WT + ((size_t)hd * F + ft * 64 + r) * F) + q * 4;
    uint4* lp = (uint4*)(As + r * LK) + q * 4;
    lp[0] = g[0]; lp[1] = g[1]; lp[2] = g[2]; lp[3] = g[3];
  }
  {  // B: 64 n rows x 128 k
    int r = tid >> 2, q = tid & 3;
    const uint4* g = (const uint4*)(hb + ((size_t)(b * N + n0 + r)) * F) + q * 4;
    uint4* lp = (uint4*)(Bs + r * LK) + q * 4;
    lp[0] = g[0]; lp[1] = g[1]; lp[2] = g[2]; lp[3] = g[3];
  }
  __syncthreads();
  int arow = lane & 15, koff = (lane >> 4) * 8;
  f32x4 acc[4] = {};
#pragma unroll
  for (int ks = 0; ks < 4; ks++) {
    short8 bb = *(const short8*)(Bs + (w * 16 + arow) * LK + ks * 32 + koff);
#pragma unroll
    for (int rt = 0; rt < 4; rt++) {
      short8 a = *(const short8*)(As + (rt * 16 + arow) * LK + ks * 32 + koff);
      acc[rt] = mfma16(a, bb, acc[rt]);
    }
  }
  short* outp = hhT + (size_t)bh * F * N;
  int crow0 = (lane >> 4) * 4;
#pragma unroll
  for (int rt = 0; rt < 4; rt++) {
    int fo = ft * 64 + rt * 16 + crow0;
    int n = n0 + w * 16 + arow;
#pragma unroll
    for (int r = 0; r < 4; r++)
      outp[(size_t)(fo + r) * N + n] = f2bf(acc[rt][r]);
  }
  // fused s1/s2 epilogue
  const float* ah = ah_base + (size_t)hd * 2 * F;
  float pa1 = 0.f, pa2 = 0.f;
#pragma unroll
  for (int rt = 0; rt < 4; rt++) {
    int fo = ft * 64 + rt * 16 + crow0;
#pragma unroll
    for (int r = 0; r < 4; r++) {
      pa1 = fmaf(ah[fo + r], acc[rt][r], pa1);
      pa2 = fmaf(ah[F + fo + r], acc[rt][r], pa2);
    }
  }
  pa1 += __shfl_xor(pa1, 16); pa1 += __shfl_xor(pa1, 32);
  pa2 += __shfl_xor(pa2, 16); pa2 += __shfl_xor(pa2, 32);
  if (lane < 16) {
    int n = n0 + w * 16 + lane;
    atomicAdd(&s1[(size_t)bh * N + n], pa1);
    atomicAdd(&s2[(size_t)bh * N + n], pa2);
  }
}

// ========= fused attention, 8 heads, single-pass softmax, ELU epilogue ====
// grid 1024 flat: bh = bid&63 (XCD-pinned), nt = bid>>6 (16 x 32-row tiles).
// V chunks of 64 cols; LDS ~26 KB -> 4 blocks/CU.
__global__ __launch_bounds__(256) void k_attn_heads4(
    const short* __restrict__ VT, const float* __restrict__ s1g,
    const float* __restrict__ s2g, const unsigned long long* __restrict__ amask,
    short* __restrict__ multi) {
  int bid = blockIdx.x;
  int bh = bid & 63, nt = bid >> 6;
  int b = bh >> 3, hd = bh & 7;
  int n0 = nt * 32;
  constexpr int LVK = 72;  // 64 cols + 8 pad (bf16)
  __shared__ short Vs[128 * LVK];   // 18432 B
  __shared__ short Pf[4 * 64 * 8];  // 4 A-frags (rt2 x ks2) = 4096 B
  __shared__ float s2all[512];
  __shared__ float s1r[32], mrow[32], linv[32];
  __shared__ float red[32][8];

  int tid = threadIdx.x, lane = tid & 63, w = tid >> 6;
  s2all[tid] = s2g[(size_t)bh * N + tid];
  s2all[tid + 256] = s2g[(size_t)bh * N + tid + 256];
  if (tid < 32) s1r[tid] = s1g[(size_t)bh * N + n0 + tid];
  __syncthreads();
  {  // prepass: per-row masked max of s2; r = tid&31, seg = tid>>5 (64 cols)
    int r = tid & 31, seg = tid >> 5;
    unsigned long long mb = amask[((size_t)(b * N + n0 + r)) * 8 + seg];
    unsigned lo = (unsigned)mb, hi = (unsigned)(mb >> 32);
    int base = seg * 64;
    float mx = FLOW;
#pragma unroll
    for (int k = 0; k < 32; k++) {
      mx = ((lo >> k) & 1u) ? fmaxf(mx, s2all[base + k]) : mx;
      mx = ((hi >> k) & 1u) ? fmaxf(mx, s2all[base + 32 + k]) : mx;
    }
    red[r][seg] = mx;
  }
  __syncthreads();
  if (tid < 32) {
    float m2 = FLOW;
#pragma unroll
    for (int k = 0; k < 8; k++) m2 = fmaxf(m2, red[tid][k]);
    float xm = s1r[tid] + m2;
    mrow[tid] = xm > 0.f ? xm : ALPHA_LR * xm;
  }
  // P-thread mapping: wave w computes A-frag w (rt = w>>1, ks = w&1);
  // row = (w>>1)*16 + (lane&15), col-slice = (w&1)*32 + (lane>>4)*8.
  int prow = ((w >> 1) << 4) | (lane & 15);
  int pcol = ((w & 1) << 5) + ((lane >> 4) << 3);
  int pg = ((w & 1) << 2) | (lane >> 4);  // col-group 0..7 for l-reduction
  const unsigned long long* mp = amask + ((size_t)(b * N + n0 + prow)) * 8;
  float lp = 0.f;
  int arow = lane & 15, koff = (lane >> 4) * 8;
  f32x4 acc[2][2] = {};
  const short* Vg = VT + (size_t)bh * F * N;
  int fr = tid >> 1, hf = tid & 1;
  for (int mc = 0; mc < 8; mc++) {
    int m0 = mc * 64;
    __syncthreads();  // A: prior MFMA done with Vs/Pf
    {                 // stage V^T chunk: 128 f x 64 m (16 KB)
      const uint4* g4 = (const uint4*)(Vg + (size_t)fr * N + m0 + hf * 32);
      uint4* l4 = (uint4*)(Vs + fr * LVK + hf * 32);
      l4[0] = g4[0]; l4[1] = g4[1]; l4[2] = g4[2]; l4[3] = g4[3];
    }
    {  // P: 8 values per thread, written directly in A-fragment order
      float s1v = s1r[prow], mr = mrow[prow];
      unsigned bits = (unsigned)((mp[mc] >> pcol) & 0xffull);
      short8 pk;
#pragma unroll
      for (int j = 0; j < 8; j++) {
        float xv = s1v + s2all[m0 + pcol + j];
        xv = xv > 0.f ? xv : ALPHA_LR * xv;
        float p = __expf(xv - mr);
        p = ((bits >> j) & 1u) ? p : 0.f;
        lp += p;
        pk[j] = f2bf(p);
      }
      *(short8*)(Pf + (w * 64 + lane) * 8) = pk;
    }
    __syncthreads();  // B
#pragma unroll
    for (int ks = 0; ks < 2; ks++) {
      short8 a0 = *(const short8*)(Pf + ((0 * 2 + ks) * 64 + lane) * 8);
      short8 a1 = *(const short8*)(Pf + ((1 * 2 + ks) * 64 + lane) * 8);
#pragma unroll
      for (int cj = 0; cj < 2; cj++) {
        short8 bb = *(const short8*)(Vs + ((w * 2 + cj) * 16 + arow) * LVK +
                                     ks * 32 + koff);
        acc[0][cj] = mfma16(a0, bb, acc[0][cj]);
        acc[1][cj] = mfma16(a1, bb, acc[1][cj]);
      }
    }
  }
  __syncthreads();
  red[prow][pg] = lp;
  __syncthreads();
  if (tid < 32) {
    float ls = 0.f;
#pragma unroll
    for (int k = 0; k < 8; k++) ls += red[tid][k];
    linv[tid] = 1.f / ls;
  }
  __syncthreads();
  int crow0 = (lane >> 4) * 4;
#pragma unroll
  for (int rt = 0; rt < 2; rt++)
#pragma unroll
    for (int cj = 0; cj < 2; cj++) {
      int fcol = (w * 2 + cj) * 16 + arow;
#pragma unroll
      for (int rr = 0; rr < 4; rr++) {
        int nrow = rt * 16 + crow0 + rr;
        float v = acc[rt][cj][rr] * linv[nrow];
        v = v > 0.f ? v : __expf(v) - 1.f;  // ELU
        multi[((size_t)(b * N + n0 + nrow)) * (H * F) + hd * F + fcol] = f2bf(v);
      }
    }
}

// ========= out projection: hsT[b][f_out][n] = WoT . multi^T, + s1/s2 ======
// grid (4, 8, B), block 256.  (R7-exact)
__global__ __launch_bounds__(256) void k_proj_out_mfma(
    const short* __restrict__ WoT, const short* __restrict__ multi,
    const float* __restrict__ ao, short* __restrict__ hsT,
    float* __restrict__ s1, float* __restrict__ s2) {
  int ft = blockIdx.x, nt = blockIdx.y, b = blockIdx.z;
  constexpr int LK = 136;
  __shared__ short As[32 * LK];
  __shared__ short Bs[64 * LK];
  int tid = threadIdx.x, lane = tid & 63, w = tid >> 6;
  int arow = lane & 15, koff = (lane >> 4) * 8;
  const int KT = H * F;  // 1024
  f32x4 acc[2] = {};
  for (int k0 = 0; k0 < KT; k0 += 128) {
    __syncthreads();
    {
      int r = tid >> 3, e = tid & 7;
      const uint4* gp = (const uint4*)(WoT + (size_t)(ft * 32 + r) * KT + k0) + e * 2;
      uint4* lp = (uint4*)(As + r * LK) + e * 2;
      lp[0] = gp[0]; lp[1] = gp[1];
    }
    {
      int r = tid >> 2, q = tid & 3;
      const uint4* gp =
          (const uint4*)(multi + (size_t)(b * N + nt * 64 + r) * KT + k0) + q * 4;
      uint4* lp = (uint4*)(Bs + r * LK) + q * 4;
      lp[0] = gp[0]; lp[1] = gp[1]; lp[2] = gp[2]; lp[3] = gp[3];
    }
    __syncthreads();
#pragma unroll
    for (int ks = 0; ks < 4; ks++) {
      short8 b0 = *(const short8*)(Bs + (w * 16 + arow) * LK + ks * 32 + koff);
      short8 a0 = *(const short8*)(As + arow * LK + ks * 32 + koff);
      short8 a1 = *(const short8*)(As + (16 + arow) * LK + ks * 32 + koff);
      acc[0] = mfma16(a0, b0, acc[0]);
      acc[1] = mfma16(a1, b0, acc[1]);
    }
  }
  int crow0 = (lane >> 4) * 4;
  short* op = hsT + (size_t)b * F * N;
#pragma unroll
  for (int rt = 0; rt < 2; rt++)
#pragma unroll
    for (int r = 0; r < 4; r++)
      op[(size_t)(ft * 32 + rt * 16 + crow0 + r) * N + nt * 64 + w * 16 + arow] =
          f2bf(acc[rt][r]);
  float pa1 = 0.f, pa2 = 0.f;
#pragma unroll
  for (int rt = 0; rt < 2; rt++) {
    int fo = ft * 32 + rt * 16 + crow0;
#pragma unroll
    for (int r = 0; r < 4; r++) {
      pa1 = fmaf(ao[fo + r], acc[rt][r], pa1);
      pa2 = fmaf(ao[F + fo + r], acc[rt][r], pa2);
    }
  }
  pa1 += __shfl_xor(pa1, 16); pa1 += __shfl_xor(pa1, 32);
  pa2 += __shfl_xor(pa2, 16); pa2 += __shfl_xor(pa2, 32);
  if (lane < 16) {
    int n = nt * 64 + w * 16 + lane;
    atomicAdd(&s1[(size_t)b * N + n], pa1);
    atomicAdd(&s2[(size_t)b * N + n], pa2);
  }
}

// ========= fused attention single head + residual + LayerNorm =============
// grid 256 flat, XCD swizzle: b = bid&7.  (R7-exact)
template <int LAST>
__global__ __launch_bounds__(256) void k_attn_single3(
    const short* __restrict__ VT, const float* __restrict__ s1g,
    const float* __restrict__ s2g, const unsigned long long* __restrict__ amask,
    const float* __restrict__ resid, const float* __restrict__ lng,
    const float* __restrict__ lnb, float* __restrict__ hout,
    short* __restrict__ hbout, float* __restrict__ dout) {
  int bid = blockIdx.x;
  int b = bid & 7, nt = bid >> 3;
  int n0 = nt * 16;
  constexpr int LVK = 136;
  __shared__ short Vs[128 * LVK];
  __shared__ short Pf[4 * 64 * 8];
  __shared__ float s2all[512];
  __shared__ float Ot[16][132];
  __shared__ float redS[16][16], redQ[16][16];
  __shared__ float s1r[16], mrow[16], linv[16], muA[16], rsA[16];

  int tid = threadIdx.x, lane = tid & 63, w = tid >> 6;
  s2all[tid] = s2g[(size_t)b * N + tid];
  s2all[tid + 256] = s2g[(size_t)b * N + tid + 256];
  if (tid < 16) s1r[tid] = s1g[(size_t)b * N + n0 + tid];
  __syncthreads();
  {
    int r = tid & 15, seg = tid >> 4;
    unsigned long long mb = amask[((size_t)(b * N + n0 + r)) * 8 + (seg >> 1)];
    unsigned bits = (unsigned)(mb >> ((seg & 1) * 32));
    float mx = FLOW;
#pragma unroll
    for (int k = 0; k < 32; k++)
      mx = ((bits >> k) & 1u) ? fmaxf(mx, s2all[seg * 32 + k]) : mx;
    redS[r][seg] = mx;
  }
  __syncthreads();
  if (tid < 16) {
    float m2 = FLOW;
#pragma unroll
    for (int k = 0; k < 16; k++) m2 = fmaxf(m2, redS[tid][k]);
    float xm = s1r[tid] + m2;
    mrow[tid] = xm > 0.f ? xm : ALPHA_LR * xm;
  }
  float lp = 0.f;
  int arow = lane & 15, koff = (lane >> 4) * 8;
  int pr = tid & 15, pq = (tid >> 4) & 3;
  f32x4 acc[2] = {};
  const short* Vg = VT + (size_t)b * F * N;
  const unsigned long long* mp = amask + ((size_t)(b * N + n0 + pr)) * 8;
  for (int mc = 0; mc < 4; mc++) {
    int m0 = mc * 128;
    __syncthreads();
    {
      int fr = tid >> 1, hf = tid & 1;
      const uint4* g4 = (const uint4*)(Vg + (size_t)fr * N + m0 + hf * 64);
      uint4* l4 = (uint4*)(Vs + fr * LVK + hf * 64);
#pragma unroll
      for (int k = 0; k < 8; k++) l4[k] = g4[k];
    }
    {
      float s1v = s1r[pr], mr = mrow[pr];
      unsigned bits = (unsigned)(mp[mc * 2 + (w >> 1)] >> ((w & 1) * 32));
      short8 pk;
#pragma unroll
      for (int j = 0; j < 8; j++) {
        float xv = s1v + s2all[m0 + w * 32 + pq * 8 + j];
        xv = xv > 0.f ? xv : ALPHA_LR * xv;
        float p = __expf(xv - mr);
        p = ((bits >> (pq * 8 + j)) & 1u) ? p : 0.f;
        lp += p;
        pk[j] = f2bf(p);
      }
      *(short8*)(Pf + (w * 64 + ((pq << 4) | pr)) * 8) = pk;
    }
    __syncthreads();
#pragma unroll
    for (int ks = 0; ks < 4; ks++) {
      short8 a = *(const short8*)(Pf + (ks * 64 + lane) * 8);
#pragma unroll
      for (int cj = 0; cj < 2; cj++) {
        short8 bb = *(const short8*)(Vs + ((w * 2 + cj) * 16 + arow) * LVK +
                                     ks * 32 + koff);
        acc[cj] = mfma16(a, bb, acc[cj]);
      }
    }
  }
  __syncthreads();
  redS[pr][tid >> 4] = lp;
  __syncthreads();
  if (tid < 16) {
    float l = 0.f;
#pragma unroll
    for (int k = 0; k < 16; k++) l += redS[tid][k];
    linv[tid] = 1.f / l;
  }
  __syncthreads();
  int crow0 = (lane >> 4) * 4;
#pragma unroll
  for (int cj = 0; cj < 2; cj++) {
    int fcol = (w * 2 + cj) * 16 + arow;
#pragma unroll
    for (int rr = 0; rr < 4; rr++) {
      int row = crow0 + rr;
      Ot[row][fcol] = acc[cj][rr] * linv[row];
    }
  }
  __syncthreads();
  int r2 = tid >> 4, f8 = (tid & 15) * 8;
  size_t gbase = ((size_t)(b * N + n0 + r2)) * F + f8;
  float v[8];
  float s = 0.f, sq = 0.f;
#pragma unroll
  for (int j = 0; j < 8; j++) {
    float t = Ot[r2][f8 + j] + resid[gbase + j];
    v[j] = t;
    s += t;
    sq = fmaf(t, t, sq);
  }
  redS[r2][tid & 15] = s;
  redQ[r2][tid & 15] = sq;
  __syncthreads();
  if (tid < 16) {
    float ss = 0.f, qq = 0.f;
#pragma unroll
    for (int k = 0; k < 16; k++) { ss += redS[tid][k]; qq += redQ[tid][k]; }
    float mu = ss * (1.f / F);
    muA[tid] = mu;
    rsA[tid] = rsqrtf(qq * (1.f / F) - mu * mu + EPS_LN);
  }
  __syncthreads();
  float mu = muA[r2], rs = rsA[r2];
#pragma unroll
  for (int j = 0; j < 8; j++) {
    float y = (v[j] - mu) * rs * lng[f8 + j] + lnb[f8 + j];
    if (LAST) {
      dout[gbase + j] = y;
    } else {
      y = fmaxf(y, 0.f);
      hout[gbase + j] = y;
      hbout[gbase + j] = f2bf(y);
    }
  }
}

extern "C" void kernel_launch(void* const* d_in, const int* in_sizes, int n_in,
                              void* d_out, int out_size, void* d_ws,
                              size_t ws_size, hipStream_t stream) {
  const float* x = (const float*)d_in[0];
  const int* adj = (const int*)d_in[1];
  const float* Wp = (const float*)d_in[2];
  const float* bp = (const float*)d_in[3];
  const float* W_heads = (const float*)d_in[4];
  const float* a_heads = (const float*)d_in[5];
  const float* W_out = (const float*)d_in[6];
  const float* a_out = (const float*)d_in[7];
  const float* ln_g = (const float*)d_in[8];
  const float* ln_b = (const float*)d_in[9];

  char* p = (char*)d_ws;
  auto alloc = [&](size_t bytes) {
    char* r = p;
    p += (bytes + 255) & ~(size_t)255;
    return r;
  };
  float* sA = (float*)alloc((size_t)2 * 73728 * 4);
  short* WTh = (short*)alloc((size_t)2 * H * F * F * 2);
  short* WoT = (short*)alloc((size_t)2 * H * F * F * 2);
  unsigned long long* amask = (unsigned long long*)alloc((size_t)BN * 8 * 8);
  float* h = (float*)alloc((size_t)BN * F * 4);
  short* hb = (short*)alloc((size_t)BN * F * 2);
  short* hhT = (short*)alloc((size_t)B * H * F * N * 2);
  short* multi = (short*)alloc((size_t)BN * H * F * 2);
  short* hsT = (short*)alloc((size_t)B * F * N * 2);

  g_setup<<<512, 256, 0, stream>>>(x, adj, Wp, bp, W_heads, W_out, h, hb,
                                   amask, WTh, WoT, sA);
  for (int l = 0; l < 2; l++) {
    float* s1h = sA + (size_t)l * 73728;
    float* s2h = s1h + 32768;
    float* s1o = s2h + 32768;
    float* s2o = s1o + 4096;
    k_proj_heads_mfma2<<<dim3(1024), 256, 0, stream>>>(
        WTh + (size_t)l * H * F * F, hb, a_heads + (size_t)l * H * 2 * F, hhT,
        s1h, s2h);
    k_attn_heads4<<<dim3(1024), 256, 0, stream>>>(hhT, s1h, s2h, amask, multi);
    k_proj_out_mfma<<<dim3(4, 8, 8), 256, 0, stream>>>(
        WoT + (size_t)l * F * H * F, multi, a_out + (size_t)l * 2 * F, hsT, s1o,
        s2o);
    if (l == 0)
      k_attn_single3<0><<<dim3(256), 256, 0, stream>>>(
          hsT, s1o, s2o, amask, h, ln_g, ln_b, h, hb, nullptr);
    else
      k_attn_single3<1><<<dim3(256), 256, 0, stream>>>(
          hsT, s1o, s2o, amask, h, ln_g + F, ln_b + F, nullptr, nullptr,
          (float*)d_out);
  }
}

// Round 9
// 178.737 us; speedup vs baseline: 1.3054x; 1.0000x over previous
//
#include <hip/hip_runtime.h>

// GAT spatio-temporal model — bf16 MFMA pipeline.
// R9: batch-pinned XCD mapping — every kernel maps blockIdx&7 -> batch b, so
// each batch's intermediates stay resident in one XCD's L2 across all stages.
// B=8, N=512, Din=64, H=8, F=128, L=2.

constexpr int B = 8, N = 512, DIN = 64, H = 8, F = 128;
constexpr int BN = B * N;          // 4096
constexpr float ALPHA_LR = 0.2f;   // LeakyReLU slope
constexpr float EPS_LN = 1e-5f;
constexpr float FLOW = -3.0e38f;   // "-inf" substitute

typedef __attribute__((ext_vector_type(8))) short short8;  // 8 bf16
typedef __attribute__((ext_vector_type(4))) float f32x4;

__device__ __forceinline__ f32x4 mfma16(short8 a, short8 b, f32x4 c) {
  return __builtin_amdgcn_mfma_f32_16x16x32_bf16(a, b, c, 0, 0, 0);
}

__device__ __forceinline__ short f2bf(float f) {  // RNE f32 -> bf16 bits
  union { float f; unsigned u; } v;
  v.f = f;
  unsigned r = v.u + 0x7FFFu + ((v.u >> 16) & 1u);
  return (short)(r >> 16);
}

// ========== setup: zero sA | adjmask | proj_in | weight transposes ========
// grid 512 x 256. proj_in rows are batch-pinned: b = bid&7.
__global__ __launch_bounds__(256) void g_setup(
    const float* __restrict__ x, const int* __restrict__ adj,
    const float* __restrict__ Wp, const float* __restrict__ bp,
    const float* __restrict__ W_heads, const float* __restrict__ W_out,
    float* __restrict__ h, short* __restrict__ hb,
    unsigned long long* __restrict__ amask, short* __restrict__ WTh,
    short* __restrict__ WoT, float* __restrict__ sA) {
  __shared__ float T[32][33];
  __shared__ float xr[2][64];
  int bid = blockIdx.x, tid = threadIdx.x;
  for (int i = tid; i < 288; i += 256) sA[(size_t)bid * 288 + i] = 0.f;
  {  // adjacency -> 64-bit masks (batched loads)
    int lane = tid & 63, wv = tid >> 6;
    int v[16];
#pragma unroll
    for (int j = 0; j < 16; j++) {
      int w = (bid + j * 512) * 4 + wv;
      v[j] = adj[(size_t)w * 64 + lane];
    }
#pragma unroll
    for (int j = 0; j < 16; j++) {
      int w = (bid + j * 512) * 4 + wv;
      unsigned long long m = __ballot(v[j] > 0);
      if (lane == 0) amask[w] = m;
    }
  }
  {  // input projection: h = relu(x@Wp+bp), 2 rows/unit, batch-pinned
    int half = tid >> 7, f = tid & 127;
    int b = bid & 7, v0 = bid >> 3;
    for (int v = v0; v < 256; v += 64) {
      int row = b * 512 + v * 2 + half;
      __syncthreads();
      if (f < 64) xr[half][f] = x[(size_t)row * DIN + f];
      __syncthreads();
      float acc = bp[f];
#pragma unroll
      for (int i = 0; i < DIN; i++)
        acc = fmaf(xr[half][i], Wp[i * F + f], acc);
      acc = fmaxf(acc, 0.f);
      h[(size_t)row * F + f] = acc;
      hb[(size_t)row * F + f] = f2bf(acc);
    }
  }
  {  // weight transposes f32 [bt][R][C] -> bf16 [bt][C][R]
    const float* in; short* out; int R, C, bx, by, bt;
    if (bid < 256) {
      in = W_heads; out = WTh; R = 128; C = 128;
      bx = bid & 3; by = (bid >> 2) & 3; bt = bid >> 4;
    } else {
      int i = bid - 256;
      in = W_out; out = WoT; R = 1024; C = 128;
      bx = i & 3; by = (i >> 2) & 31; bt = i >> 7;
    }
    int c0 = bx * 32, r0 = by * 32;
    const float* ip = in + (size_t)bt * R * C;
    short* op = out + (size_t)bt * R * C;
    __syncthreads();
    {
      int r = tid >> 3, c4 = (tid & 7) * 4;
      float4 v = *(const float4*)(ip + (size_t)(r0 + r) * C + c0 + c4);
      T[r][c4] = v.x; T[r][c4 + 1] = v.y; T[r][c4 + 2] = v.z; T[r][c4 + 3] = v.w;
    }
    __syncthreads();
    {
      int cr = tid >> 3, q = (tid & 7) * 4;
      short4 o;
      o.x = f2bf(T[q][cr]); o.y = f2bf(T[q + 1][cr]);
      o.z = f2bf(T[q + 2][cr]); o.w = f2bf(T[q + 3][cr]);
      *(short4*)(op + (size_t)(c0 + cr) * R + r0 + q) = o;
    }
  }
}

// ========= head projection: hhT[bh][f_out][n] = WT[h] . hb^T, + s1/s2 =====
// grid 1024 flat, batch-pinned: b = bid&7, hd = (bid>>3)&7, ft = (bid>>6)&1,
// nt = bid>>7. Tile 64 f_out x 64 n.
__global__ __launch_bounds__(256) void k_proj_heads_mfma2(
    const short* __restrict__ WT, const short* __restrict__ hb,
    const float* __restrict__ ah_base, short* __restrict__ hhT,
    float* __restrict__ s1, float* __restrict__ s2) {
  int bid = blockIdx.x;
  int b = bid & 7, hd = (bid >> 3) & 7, ft = (bid >> 6) & 1, nt = bid >> 7;
  int bh = b * 8 + hd;
  int n0 = nt * 64;
  constexpr int LK = 136;
  __shared__ short As[64 * LK];
  __shared__ short Bs[64 * LK];
  int tid = threadIdx.x, lane = tid & 63, w = tid >> 6;
  {  // A: 64 f_out rows x 128 k
    int r = tid >> 2, q = tid & 3;
    const uint4* g = (const uint4*)(WT + ((size_t)hd * F + ft * 64 + r) * F) + q * 4;
    uint4* lp = (uint4*)(As + r * LK) + q * 4;
    lp[0] = g[0]; lp[1] = g[1]; lp[2] = g[2]; lp[3] = g[3];
  }
  {  // B: 64 n rows x 128 k
    int r = tid >> 2, q = tid & 3;
    const uint4* g = (const uint4*)(hb + ((size_t)(b * N + n0 + r)) * F) + q * 4;
    uint4* lp = (uint4*)(Bs + r * LK) + q * 4;
    lp[0] = g[0]; lp[1] = g[1]; lp[2] = g[2]; lp[3] = g[3];
  }
  __syncthreads();
  int arow = lane & 15, koff = (lane >> 4) * 8;
  f32x4 acc[4] = {};
#pragma unroll
  for (int ks = 0; ks < 4; ks++) {
    short8 bb = *(const short8*)(Bs + (w * 16 + arow) * LK + ks * 32 + koff);
#pragma unroll
    for (int rt = 0; rt < 4; rt++) {
      short8 a = *(const short8*)(As + (rt * 16 + arow) * LK + ks * 32 + koff);
      acc[rt] = mfma16(a, bb, acc[rt]);
    }
  }
  short* outp = hhT + (size_t)bh * F * N;
  int crow0 = (lane >> 4) * 4;
#pragma unroll
  for (int rt = 0; rt < 4; rt++) {
    int fo = ft * 64 + rt * 16 + crow0;
    int n = n0 + w * 16 + arow;
#pragma unroll
    for (int r = 0; r < 4; r++)
      outp[(size_t)(fo + r) * N + n] = f2bf(acc[rt][r]);
  }
  // fused s1/s2 epilogue
  const float* ah = ah_base + (size_t)hd * 2 * F;
  float pa1 = 0.f, pa2 = 0.f;
#pragma unroll
  for (int rt = 0; rt < 4; rt++) {
    int fo = ft * 64 + rt * 16 + crow0;
#pragma unroll
    for (int r = 0; r < 4; r++) {
      pa1 = fmaf(ah[fo + r], acc[rt][r], pa1);
      pa2 = fmaf(ah[F + fo + r], acc[rt][r], pa2);
    }
  }
  pa1 += __shfl_xor(pa1, 16); pa1 += __shfl_xor(pa1, 32);
  pa2 += __shfl_xor(pa2, 16); pa2 += __shfl_xor(pa2, 32);
  if (lane < 16) {
    int n = n0 + w * 16 + lane;
    atomicAdd(&s1[(size_t)bh * N + n], pa1);
    atomicAdd(&s2[(size_t)bh * N + n], pa2);
  }
}

// ========= fused attention, 8 heads, single-pass softmax, ELU epilogue ====
// grid 1024 flat, batch-pinned: b = bid&7, hd = (bid>>3)&7, nt = bid>>6.
// 32-row Q-tiles, V chunks of 64 cols.
__global__ __launch_bounds__(256) void k_attn_heads4(
    const short* __restrict__ VT, const float* __restrict__ s1g,
    const float* __restrict__ s2g, const unsigned long long* __restrict__ amask,
    short* __restrict__ multi) {
  int bid = blockIdx.x;
  int b = bid & 7, hd = (bid >> 3) & 7, nt = bid >> 6;
  int bh = b * 8 + hd;
  int n0 = nt * 32;
  constexpr int LVK = 72;  // 64 cols + 8 pad (bf16)
  __shared__ short Vs[128 * LVK];   // 18432 B
  __shared__ short Pf[4 * 64 * 8];  // 4096 B
  __shared__ float s2all[512];
  __shared__ float s1r[32], mrow[32], linv[32];
  __shared__ float red[32][8];

  int tid = threadIdx.x, lane = tid & 63, w = tid >> 6;
  s2all[tid] = s2g[(size_t)bh * N + tid];
  s2all[tid + 256] = s2g[(size_t)bh * N + tid + 256];
  if (tid < 32) s1r[tid] = s1g[(size_t)bh * N + n0 + tid];
  __syncthreads();
  {  // prepass: per-row masked max of s2
    int r = tid & 31, seg = tid >> 5;
    unsigned long long mb = amask[((size_t)(b * N + n0 + r)) * 8 + seg];
    unsigned lo = (unsigned)mb, hi = (unsigned)(mb >> 32);
    int base = seg * 64;
    float mx = FLOW;
#pragma unroll
    for (int k = 0; k < 32; k++) {
      mx = ((lo >> k) & 1u) ? fmaxf(mx, s2all[base + k]) : mx;
      mx = ((hi >> k) & 1u) ? fmaxf(mx, s2all[base + 32 + k]) : mx;
    }
    red[r][seg] = mx;
  }
  __syncthreads();
  if (tid < 32) {
    float m2 = FLOW;
#pragma unroll
    for (int k = 0; k < 8; k++) m2 = fmaxf(m2, red[tid][k]);
    float xm = s1r[tid] + m2;
    mrow[tid] = xm > 0.f ? xm : ALPHA_LR * xm;
  }
  int prow = ((w >> 1) << 4) | (lane & 15);
  int pcol = ((w & 1) << 5) + ((lane >> 4) << 3);
  int pg = ((w & 1) << 2) | (lane >> 4);
  const unsigned long long* mp = amask + ((size_t)(b * N + n0 + prow)) * 8;
  float lp = 0.f;
  int arow = lane & 15, koff = (lane >> 4) * 8;
  f32x4 acc[2][2] = {};
  const short* Vg = VT + (size_t)bh * F * N;
  int fr = tid >> 1, hf = tid & 1;
  for (int mc = 0; mc < 8; mc++) {
    int m0 = mc * 64;
    __syncthreads();  // A
    {                 // stage V^T chunk: 128 f x 64 m
      const uint4* g4 = (const uint4*)(Vg + (size_t)fr * N + m0 + hf * 32);
      uint4* l4 = (uint4*)(Vs + fr * LVK + hf * 32);
      l4[0] = g4[0]; l4[1] = g4[1]; l4[2] = g4[2]; l4[3] = g4[3];
    }
    {  // P in A-fragment order
      float s1v = s1r[prow], mr = mrow[prow];
      unsigned bits = (unsigned)((mp[mc] >> pcol) & 0xffull);
      short8 pk;
#pragma unroll
      for (int j = 0; j < 8; j++) {
        float xv = s1v + s2all[m0 + pcol + j];
        xv = xv > 0.f ? xv : ALPHA_LR * xv;
        float p = __expf(xv - mr);
        p = ((bits >> j) & 1u) ? p : 0.f;
        lp += p;
        pk[j] = f2bf(p);
      }
      *(short8*)(Pf + (w * 64 + lane) * 8) = pk;
    }
    __syncthreads();  // B
#pragma unroll
    for (int ks = 0; ks < 2; ks++) {
      short8 a0 = *(const short8*)(Pf + ((0 * 2 + ks) * 64 + lane) * 8);
      short8 a1 = *(const short8*)(Pf + ((1 * 2 + ks) * 64 + lane) * 8);
#pragma unroll
      for (int cj = 0; cj < 2; cj++) {
        short8 bb = *(const short8*)(Vs + ((w * 2 + cj) * 16 + arow) * LVK +
                                     ks * 32 + koff);
        acc[0][cj] = mfma16(a0, bb, acc[0][cj]);
        acc[1][cj] = mfma16(a1, bb, acc[1][cj]);
      }
    }
  }
  __syncthreads();
  red[prow][pg] = lp;
  __syncthreads();
  if (tid < 32) {
    float ls = 0.f;
#pragma unroll
    for (int k = 0; k < 8; k++) ls += red[tid][k];
    linv[tid] = 1.f / ls;
  }
  __syncthreads();
  int crow0 = (lane >> 4) * 4;
#pragma unroll
  for (int rt = 0; rt < 2; rt++)
#pragma unroll
    for (int cj = 0; cj < 2; cj++) {
      int fcol = (w * 2 + cj) * 16 + arow;
#pragma unroll
      for (int rr = 0; rr < 4; rr++) {
        int nrow = rt * 16 + crow0 + rr;
        float v = acc[rt][cj][rr] * linv[nrow];
        v = v > 0.f ? v : __expf(v) - 1.f;  // ELU
        multi[((size_t)(b * N + n0 + nrow)) * (H * F) + hd * F + fcol] = f2bf(v);
      }
    }
}

// ========= out projection: hsT[b][f_out][n] = WoT . multi^T, + s1/s2 ======
// grid 256 flat, batch-pinned: b = bid&7, ft = (bid>>3)&3, nt = bid>>5.
// Tile 32 f_out x 64 n, K=1024.
__global__ __launch_bounds__(256) void k_proj_out_mfma(
    const short* __restrict__ WoT, const short* __restrict__ multi,
    const float* __restrict__ ao, short* __restrict__ hsT,
    float* __restrict__ s1, float* __restrict__ s2) {
  int bid = blockIdx.x;
  int b = bid & 7, ft = (bid >> 3) & 3, nt = bid >> 5;
  constexpr int LK = 136;
  __shared__ short As[32 * LK];
  __shared__ short Bs[64 * LK];
  int tid = threadIdx.x, lane = tid & 63, w = tid >> 6;
  int arow = lane & 15, koff = (lane >> 4) * 8;
  const int KT = H * F;  // 1024
  f32x4 acc[2] = {};
  for (int k0 = 0; k0 < KT; k0 += 128) {
    __syncthreads();
    {
      int r = tid >> 3, e = tid & 7;
      const uint4* gp = (const uint4*)(WoT + (size_t)(ft * 32 + r) * KT + k0) + e * 2;
      uint4* lp = (uint4*)(As + r * LK) + e * 2;
      lp[0] = gp[0]; lp[1] = gp[1];
    }
    {
      int r = tid >> 2, q = tid & 3;
      const uint4* gp =
          (const uint4*)(multi + (size_t)(b * N + nt * 64 + r) * KT + k0) + q * 4;
      uint4* lp = (uint4*)(Bs + r * LK) + q * 4;
      lp[0] = gp[0]; lp[1] = gp[1]; lp[2] = gp[2]; lp[3] = gp[3];
    }
    __syncthreads();
#pragma unroll
    for (int ks = 0; ks < 4; ks++) {
      short8 b0 = *(const short8*)(Bs + (w * 16 + arow) * LK + ks * 32 + koff);
      short8 a0 = *(const short8*)(As + arow * LK + ks * 32 + koff);
      short8 a1 = *(const short8*)(As + (16 + arow) * LK + ks * 32 + koff);
      acc[0] = mfma16(a0, b0, acc[0]);
      acc[1] = mfma16(a1, b0, acc[1]);
    }
  }
  int crow0 = (lane >> 4) * 4;
  short* op = hsT + (size_t)b * F * N;
#pragma unroll
  for (int rt = 0; rt < 2; rt++)
#pragma unroll
    for (int r = 0; r < 4; r++)
      op[(size_t)(ft * 32 + rt * 16 + crow0 + r) * N + nt * 64 + w * 16 + arow] =
          f2bf(acc[rt][r]);
  float pa1 = 0.f, pa2 = 0.f;
#pragma unroll
  for (int rt = 0; rt < 2; rt++) {
    int fo = ft * 32 + rt * 16 + crow0;
#pragma unroll
    for (int r = 0; r < 4; r++) {
      pa1 = fmaf(ao[fo + r], acc[rt][r], pa1);
      pa2 = fmaf(ao[F + fo + r], acc[rt][r], pa2);
    }
  }
  pa1 += __shfl_xor(pa1, 16); pa1 += __shfl_xor(pa1, 32);
  pa2 += __shfl_xor(pa2, 16); pa2 += __shfl_xor(pa2, 32);
  if (lane < 16) {
    int n = nt * 64 + w * 16 + lane;
    atomicAdd(&s1[(size_t)b * N + n], pa1);
    atomicAdd(&s2[(size_t)b * N + n], pa2);
  }
}

// ========= fused attention single head + residual + LayerNorm =============
// grid 256 flat, batch-pinned: b = bid&7.  (R8-exact)
template <int LAST>
__global__ __launch_bounds__(256) void k_attn_single3(
    const short* __restrict__ VT, const float* __restrict__ s1g,
    const float* __restrict__ s2g, const unsigned long long* __restrict__ amask,
    const float* __restrict__ resid, const float* __restrict__ lng,
    const float* __restrict__ lnb, float* __restrict__ hout,
    short* __restrict__ hbout, float* __restrict__ dout) {
  int bid = blockIdx.x;
  int b = bid & 7, nt = bid >> 3;
  int n0 = nt * 16;
  constexpr int LVK = 136;
  __shared__ short Vs[128 * LVK];
  __shared__ short Pf[4 * 64 * 8];
  __shared__ float s2all[512];
  __shared__ float Ot[16][132];
  __shared__ float redS[16][16], redQ[16][16];
  __shared__ float s1r[16], mrow[16], linv[16], muA[16], rsA[16];

  int tid = threadIdx.x, lane = tid & 63, w = tid >> 6;
  s2all[tid] = s2g[(size_t)b * N + tid];
  s2all[tid + 256] = s2g[(size_t)b * N + tid + 256];
  if (tid < 16) s1r[tid] = s1g[(size_t)b * N + n0 + tid];
  __syncthreads();
  {
    int r = tid & 15, seg = tid >> 4;
    unsigned long long mb = amask[((size_t)(b * N + n0 + r)) * 8 + (seg >> 1)];
    unsigned bits = (unsigned)(mb >> ((seg & 1) * 32));
    float mx = FLOW;
#pragma unroll
    for (int k = 0; k < 32; k++)
      mx = ((bits >> k) & 1u) ? fmaxf(mx, s2all[seg * 32 + k]) : mx;
    redS[r][seg] = mx;
  }
  __syncthreads();
  if (tid < 16) {
    float m2 = FLOW;
#pragma unroll
    for (int k = 0; k < 16; k++) m2 = fmaxf(m2, redS[tid][k]);
    float xm = s1r[tid] + m2;
    mrow[tid] = xm > 0.f ? xm : ALPHA_LR * xm;
  }
  float lp = 0.f;
  int arow = lane & 15, koff = (lane >> 4) * 8;
  int pr = tid & 15, pq = (tid >> 4) & 3;
  f32x4 acc[2] = {};
  const short* Vg = VT + (size_t)b * F * N;
  const unsigned long long* mp = amask + ((size_t)(b * N + n0 + pr)) * 8;
  for (int mc = 0; mc < 4; mc++) {
    int m0 = mc * 128;
    __syncthreads();
    {
      int fr = tid >> 1, hf = tid & 1;
      const uint4* g4 = (const uint4*)(Vg + (size_t)fr * N + m0 + hf * 64);
      uint4* l4 = (uint4*)(Vs + fr * LVK + hf * 64);
#pragma unroll
      for (int k = 0; k < 8; k++) l4[k] = g4[k];
    }
    {
      float s1v = s1r[pr], mr = mrow[pr];
      unsigned bits = (unsigned)(mp[mc * 2 + (w >> 1)] >> ((w & 1) * 32));
      short8 pk;
#pragma unroll
      for (int j = 0; j < 8; j++) {
        float xv = s1v + s2all[m0 + w * 32 + pq * 8 + j];
        xv = xv > 0.f ? xv : ALPHA_LR * xv;
        float p = __expf(xv - mr);
        p = ((bits >> (pq * 8 + j)) & 1u) ? p : 0.f;
        lp += p;
        pk[j] = f2bf(p);
      }
      *(short8*)(Pf + (w * 64 + ((pq << 4) | pr)) * 8) = pk;
    }
    __syncthreads();
#pragma unroll
    for (int ks = 0; ks < 4; ks++) {
      short8 a = *(const short8*)(Pf + (ks * 64 + lane) * 8);
#pragma unroll
      for (int cj = 0; cj < 2; cj++) {
        short8 bb = *(const short8*)(Vs + ((w * 2 + cj) * 16 + arow) * LVK +
                                     ks * 32 + koff);
        acc[cj] = mfma16(a, bb, acc[cj]);
      }
    }
  }
  __syncthreads();
  redS[pr][tid >> 4] = lp;
  __syncthreads();
  if (tid < 16) {
    float l = 0.f;
#pragma unroll
    for (int k = 0; k < 16; k++) l += redS[tid][k];
    linv[tid] = 1.f / l;
  }
  __syncthreads();
  int crow0 = (lane >> 4) * 4;
#pragma unroll
  for (int cj = 0; cj < 2; cj++) {
    int fcol = (w * 2 + cj) * 16 + arow;
#pragma unroll
    for (int rr = 0; rr < 4; rr++) {
      int row = crow0 + rr;
      Ot[row][fcol] = acc[cj][rr] * linv[row];
    }
  }
  __syncthreads();
  int r2 = tid >> 4, f8 = (tid & 15) * 8;
  size_t gbase = ((size_t)(b * N + n0 + r2)) * F + f8;
  float v[8];
  float s = 0.f, sq = 0.f;
#pragma unroll
  for (int j = 0; j < 8; j++) {
    float t = Ot[r2][f8 + j] + resid[gbase + j];
    v[j] = t;
    s += t;
    sq = fmaf(t, t, sq);
  }
  redS[r2][tid & 15] = s;
  redQ[r2][tid & 15] = sq;
  __syncthreads();
  if (tid < 16) {
    float ss = 0.f, qq = 0.f;
#pragma unroll
    for (int k = 0; k < 16; k++) { ss += redS[tid][k]; qq += redQ[tid][k]; }
    float mu = ss * (1.f / F);
    muA[tid] = mu;
    rsA[tid] = rsqrtf(qq * (1.f / F) - mu * mu + EPS_LN);
  }
  __syncthreads();
  float mu = muA[r2], rs = rsA[r2];
#pragma unroll
  for (int j = 0; j < 8; j++) {
    float y = (v[j] - mu) * rs * lng[f8 + j] + lnb[f8 + j];
    if (LAST) {
      dout[gbase + j] = y;
    } else {
      y = fmaxf(y, 0.f);
      hout[gbase + j] = y;
      hbout[gbase + j] = f2bf(y);
    }
  }
}

extern "C" void kernel_launch(void* const* d_in, const int* in_sizes, int n_in,
                              void* d_out, int out_size, void* d_ws,
                              size_t ws_size, hipStream_t stream) {
  const float* x = (const float*)d_in[0];
  const int* adj = (const int*)d_in[1];
  const float* Wp = (const float*)d_in[2];
  const float* bp = (const float*)d_in[3];
  const float* W_heads = (const float*)d_in[4];
  const float* a_heads = (const float*)d_in[5];
  const float* W_out = (const float*)d_in[6];
  const float* a_out = (const float*)d_in[7];
  const float* ln_g = (const float*)d_in[8];
  const float* ln_b = (const float*)d_in[9];

  char* p = (char*)d_ws;
  auto alloc = [&](size_t bytes) {
    char* r = p;
    p += (bytes + 255) & ~(size_t)255;
    return r;
  };
  float* sA = (float*)alloc((size_t)2 * 73728 * 4);
  short* WTh = (short*)alloc((size_t)2 * H * F * F * 2);
  short* WoT = (short*)alloc((size_t)2 * H * F * F * 2);
  unsigned long long* amask = (unsigned long long*)alloc((size_t)BN * 8 * 8);
  float* h = (float*)alloc((size_t)BN * F * 4);
  short* hb = (short*)alloc((size_t)BN * F * 2);
  short* hhT = (short*)alloc((size_t)B * H * F * N * 2);
  short* multi = (short*)alloc((size_t)BN * H * F * 2);
  short* hsT = (short*)alloc((size_t)B * F * N * 2);

  g_setup<<<512, 256, 0, stream>>>(x, adj, Wp, bp, W_heads, W_out, h, hb,
                                   amask, WTh, WoT, sA);
  for (int l = 0; l < 2; l++) {
    float* s1h = sA + (size_t)l * 73728;
    float* s2h = s1h + 32768;
    float* s1o = s2h + 32768;
    float* s2o = s1o + 4096;
    k_proj_heads_mfma2<<<dim3(1024), 256, 0, stream>>>(
        WTh + (size_t)l * H * F * F, hb, a_heads + (size_t)l * H * 2 * F, hhT,
        s1h, s2h);
    k_attn_heads4<<<dim3(1024), 256, 0, stream>>>(hhT, s1h, s2h, amask, multi);
    k_proj_out_mfma<<<dim3(256), 256, 0, stream>>>(
        WoT + (size_t)l * F * H * F, multi, a_out + (size_t)l * 2 * F, hsT, s1o,
        s2o);
    if (l == 0)
      k_attn_single3<0><<<dim3(256), 256, 0, stream>>>(
          hsT, s1o, s2o, amask, h, ln_g, ln_b, h, hb, nullptr);
    else
      k_attn_single3<1><<<dim3(256), 256, 0, stream>>>(
          hsT, s1o, s2o, amask, h, ln_g + F, ln_b + F, nullptr, nullptr,
          (float*)d_out);
  }
}